// Round 1
// baseline (770.096 us; speedup 1.0000x reference)
//
#include <hip/hip_runtime.h>
#include <hip/hip_bf16.h>

typedef __bf16 bf16;
typedef __bf16 bf16x8 __attribute__((ext_vector_type(8)));
typedef __bf16 bf16x4 __attribute__((ext_vector_type(4)));
typedef float  f32x4  __attribute__((ext_vector_type(4)));

#define NL 128
#define NN 10000
#define NE 160000
#define LN_EPS 1e-5f

__device__ __forceinline__ f32x4 f4zero() {
    f32x4 v; v[0] = 0.f; v[1] = 0.f; v[2] = 0.f; v[3] = 0.f; return v;
}

// LDS tiles are [row][128] bf16 (256B row stride); byte offset within a row is
// XOR-swizzled by ((row&7)<<4) to avoid the 16-way bank conflict of stride-256B
// ds_read_b128 fragment loads (guide §6 G4 / T2).
__device__ __forceinline__ int swz_off(int row, int b) {
    return row * 256 + (b ^ ((row & 7) << 4));
}

// MFMA 16x16x32 fragment: lane l holds row (l&15), k = (l>>4)*8 + j (contiguous 8)
__device__ __forceinline__ bf16x8 frag_ld(const bf16* base, int row, int kbyte) {
    return *reinterpret_cast<const bf16x8*>(
        reinterpret_cast<const char*>(base) + swz_off(row, kbyte));
}

// Stage W[128][128] f32 row-major (k-major) global -> LDS Wt[col][k] bf16 swizzled.
template <int NT>
__device__ __forceinline__ void stage_w_t(const float* __restrict__ Wg, bf16* sWt, int tid) {
    for (int i = 0; i < 4096 / NT; ++i) {
        int q = tid + i * NT;
        int col = q & 127;
        int k0 = (q >> 7) << 2;
        bf16x4 v;
        v[0] = (bf16)Wg[(k0 + 0) * 128 + col];
        v[1] = (bf16)Wg[(k0 + 1) * 128 + col];
        v[2] = (bf16)Wg[(k0 + 2) * 128 + col];
        v[3] = (bf16)Wg[(k0 + 3) * 128 + col];
        *reinterpret_cast<bf16x4*>(reinterpret_cast<char*>(sWt) + swz_off(col, k0 * 2)) = v;
    }
}

// Stage 16 rows x 128 f32 -> bf16 LDS rows [wrow0 .. wrow0+15], one wave.
__device__ __forceinline__ void stage_rows16(const float* __restrict__ src0, bf16* sX,
                                             int wrow0, int lane) {
    int c8 = (lane & 15) * 8;
    #pragma unroll
    for (int i = 0; i < 4; ++i) {
        int sub = i * 4 + (lane >> 4);
        const float* src = src0 + (size_t)sub * 128 + c8;
        f32x4 a = *reinterpret_cast<const f32x4*>(src);
        f32x4 b = *reinterpret_cast<const f32x4*>(src + 4);
        bf16x8 v;
        v[0] = (bf16)a[0]; v[1] = (bf16)a[1]; v[2] = (bf16)a[2]; v[3] = (bf16)a[3];
        v[4] = (bf16)b[0]; v[5] = (bf16)b[1]; v[6] = (bf16)b[2]; v[7] = (bf16)b[3];
        *reinterpret_cast<bf16x8*>(reinterpret_cast<char*>(sX) + swz_off(wrow0 + sub, c8 * 2)) = v;
    }
}

// One wave: 16 rows x 128 cols, K=128.  arow = wrow0 + (lane&15), kq = (lane>>4)*16 bytes.
__device__ __forceinline__ void mfma_16x128(const bf16* sA, const bf16* sB, int arow, int kq,
                                            f32x4 acc[8]) {
    #pragma unroll
    for (int kk = 0; kk < 4; ++kk) {
        bf16x8 af = frag_ld(sA, arow, kk * 64 + kq);
        #pragma unroll
        for (int t = 0; t < 8; ++t) {
            bf16x8 bfr = frag_ld(sB, t * 16 + (arow & 15), kk * 64 + kq);
            acc[t] = __builtin_amdgcn_mfma_f32_16x16x32_bf16(af, bfr, acc[t], 0, 0, 0);
        }
    }
}

// C layout: col = (lane&15)+16t, row = (lane>>4)*4 + r  (m89-verified)
__device__ __forceinline__ void write_acc(float* dst, const f32x4 acc[8], int lane) {
    #pragma unroll
    for (int r = 0; r < 4; ++r) {
        int sub = (lane >> 4) * 4 + r;
        float* row = dst + (size_t)sub * 128 + (lane & 15);
        #pragma unroll
        for (int t = 0; t < 8; ++t) row[t * 16] = acc[t][r];
    }
}

// ---------------- embed kernels ----------------

__global__ void k_embed_nodes(const float* __restrict__ nodes, const float* __restrict__ W,
                              const float* __restrict__ b, float* __restrict__ n_out) {
    __shared__ float sW[64 * 128];
    __shared__ float sB[128];
    const int tid = threadIdx.x;
    for (int i = tid; i < 64 * 128; i += 256) sW[i] = W[i];
    if (tid < 128) sB[tid] = b[tid];
    __syncthreads();
    const int col = tid & 127;
    const int rh = tid >> 7;
    const int rowbase = blockIdx.x * 64;
    for (int i = 0; i < 32; ++i) {
        int row = rowbase + i * 2 + rh;
        if (row < NN) {
            const f32x4* x4 = reinterpret_cast<const f32x4*>(nodes + (size_t)row * 64);
            float a = sB[col];
            #pragma unroll
            for (int k4 = 0; k4 < 16; ++k4) {
                f32x4 xv = x4[k4];
                a += xv[0] * sW[(k4 * 4 + 0) * 128 + col];
                a += xv[1] * sW[(k4 * 4 + 1) * 128 + col];
                a += xv[2] * sW[(k4 * 4 + 2) * 128 + col];
                a += xv[3] * sW[(k4 * 4 + 3) * 128 + col];
            }
            n_out[(size_t)row * 128 + col] = a;
        }
    }
}

__global__ void k_embed_edges(const float* __restrict__ edges, const float* __restrict__ W,
                              const float* __restrict__ b, float* __restrict__ e_out) {
    __shared__ float sW[16 * 128];
    __shared__ float sB[128];
    const int tid = threadIdx.x;
    for (int i = tid; i < 16 * 128; i += 256) sW[i] = W[i];
    if (tid < 128) sB[tid] = b[tid];
    __syncthreads();
    const int col = tid & 127;
    const int rh = tid >> 7;
    const int rowbase = blockIdx.x * 128;
    for (int i = 0; i < 64; ++i) {
        int row = rowbase + i * 2 + rh;
        const f32x4* x4 = reinterpret_cast<const f32x4*>(edges + (size_t)row * 16);
        float a = sB[col];
        #pragma unroll
        for (int k4 = 0; k4 < 4; ++k4) {
            f32x4 xv = x4[k4];
            a += xv[0] * sW[(k4 * 4 + 0) * 128 + col];
            a += xv[1] * sW[(k4 * 4 + 1) * 128 + col];
            a += xv[2] * sW[(k4 * 4 + 2) * 128 + col];
            a += xv[3] * sW[(k4 * 4 + 3) * 128 + col];
        }
        e_out[(size_t)row * 128 + col] = a;
    }
}

__global__ void k_init_glob(const float* __restrict__ globals_, const float* __restrict__ embW,
                            const float* __restrict__ embB, float* __restrict__ g,
                            const float* __restrict__ eW0g, const float* __restrict__ eb0,
                            const float* __restrict__ nW0g, const float* __restrict__ nb0,
                            float* __restrict__ gvec_e, float* __restrict__ gvec_n) {
    __shared__ float sG[128];
    const int tid = threadIdx.x;  // 128 threads
    float a = embB[tid];
    #pragma unroll
    for (int k = 0; k < 8; ++k) a += globals_[k] * embW[k * 128 + tid];
    g[tid] = a;
    sG[tid] = a;
    __syncthreads();
    float ae = eb0[tid], an = nb0[tid];
    for (int k = 0; k < 128; ++k) {
        float gv = sG[k];
        ae += gv * eW0g[k * 128 + tid];
        an += gv * nW0g[k * 128 + tid];
    }
    gvec_e[tid] = ae;
    gvec_n[tid] = an;
}

// ---------------- per-step kernels ----------------

// nsW = n @ W0b,  nrW = n @ W0c   (edge-MLP node projections)
__global__ __launch_bounds__(256, 2) void k_proj(const float* __restrict__ n_in,
                                                 float* __restrict__ nsW, float* __restrict__ nrW,
                                                 const float* __restrict__ Wns,
                                                 const float* __restrict__ Wnr) {
    __shared__ bf16 sWa[128 * 128];
    __shared__ bf16 sWb[128 * 128];
    __shared__ bf16 sX[64 * 128];
    const int tid = threadIdx.x;
    const int lane = tid & 63;
    const int w = tid >> 6;
    const int rowbase = blockIdx.x * 64;
    const bool wvalid = (rowbase + w * 16) < NN;

    stage_w_t<256>(Wns, sWa, tid);
    stage_w_t<256>(Wnr, sWb, tid);
    if (wvalid) stage_rows16(n_in + (size_t)(rowbase + w * 16) * 128, sX, w * 16, lane);
    __syncthreads();
    if (!wvalid) return;

    const int arow = w * 16 + (lane & 15);
    const int kq = (lane >> 4) * 16;
    f32x4 acc[8];
    #pragma unroll
    for (int t = 0; t < 8; ++t) acc[t] = f4zero();
    mfma_16x128(sX, sWa, arow, kq, acc);
    write_acc(nsW + (size_t)(rowbase + w * 16) * 128, acc, lane);
    #pragma unroll
    for (int t = 0; t < 8; ++t) acc[t] = f4zero();
    mfma_16x128(sX, sWb, arow, kq, acc);
    write_acc(nrW + (size_t)(rowbase + w * 16) * 128, acc, lane);
}

// Edge update: e_new = relu(relu(e@W0a + nsW[snd] + nrW[rcv] + gvec)@W1 + b1)
// + atomic segment sums (sent/recv), block-reduced edge_agg, residual + LN in place.
__global__ __launch_bounds__(512, 2) void k_edge(
    float* e_rw, const float* __restrict__ nsW, const float* __restrict__ nrW,
    float* __restrict__ sent_agg, float* __restrict__ recv_agg, float* __restrict__ edge_agg,
    const int* __restrict__ senders, const int* __restrict__ receivers,
    const float* __restrict__ W0a, const float* __restrict__ W1,
    const float* __restrict__ gvec, const float* __restrict__ b1,
    const float* __restrict__ lnS, const float* __restrict__ lnO) {
    __shared__ bf16 sW0[128 * 128];
    __shared__ bf16 sW1[128 * 128];
    __shared__ bf16 sX[128 * 128];
    __shared__ int sSnd[128], sRcv[128];
    __shared__ float sGv[128], sB1[128], sS[128], sO[128];
    __shared__ float sEagg[8][128];

    const int tid = threadIdx.x;
    const int lane = tid & 63;
    const int w = tid >> 6;  // 0..7
    const int rowbase = blockIdx.x * 128;

    stage_w_t<512>(W0a, sW0, tid);
    stage_w_t<512>(W1, sW1, tid);
    if (tid < 128) {
        sSnd[tid] = senders[rowbase + tid];
        sRcv[tid] = receivers[rowbase + tid];
        sGv[tid] = gvec[tid];
        sB1[tid] = b1[tid];
        sS[tid] = lnS[tid];
        sO[tid] = lnO[tid];
    }
    for (int i = tid; i < 8 * 128; i += 512) (&sEagg[0][0])[i] = 0.f;
    __syncthreads();

    // stage this wave's 16 rows of e
    stage_rows16(e_rw + (size_t)(rowbase + w * 16) * 128, sX, w * 16, lane);

    const int arow = w * 16 + (lane & 15);
    const int kq = (lane >> 4) * 16;
    const int c0 = lane & 15;

    // layer 0
    f32x4 acc[8];
    #pragma unroll
    for (int t = 0; t < 8; ++t) acc[t] = f4zero();
    mfma_16x128(sX, sW0, arow, kq, acc);

    // fixup: h = relu(acc + nsW[snd] + nrW[rcv] + gvec) -> overwrite sX rows (wave-private)
    #pragma unroll
    for (int r = 0; r < 4; ++r) {
        int rl = w * 16 + (lane >> 4) * 4 + r;
        int snd = sSnd[rl], rcv = sRcv[rl];
        const float* nsp = nsW + (size_t)snd * 128;
        const float* nrp = nrW + (size_t)rcv * 128;
        #pragma unroll
        for (int t = 0; t < 8; ++t) {
            int col = t * 16 + c0;
            float v = acc[t][r] + nsp[col] + nrp[col] + sGv[col];
            v = fmaxf(v, 0.f);
            *reinterpret_cast<bf16*>(reinterpret_cast<char*>(sX) + swz_off(rl, col * 2)) = (bf16)v;
        }
    }

    // layer 1
    f32x4 acc2[8];
    #pragma unroll
    for (int t = 0; t < 8; ++t) acc2[t] = f4zero();
    mfma_16x128(sX, sW1, arow, kq, acc2);

    // epilogue: e_new = relu(acc2 + b1); atomics; residual + LN; write e
    {
        float colsum[8];
        #pragma unroll
        for (int t = 0; t < 8; ++t) colsum[t] = 0.f;
        float mean_r[4], rstd_r[4];
        #pragma unroll
        for (int r = 0; r < 4; ++r) {
            int rl = w * 16 + (lane >> 4) * 4 + r;
            size_t grow = (size_t)(rowbase + rl);
            int snd = sSnd[rl], rcv = sRcv[rl];
            float* sap = sent_agg + (size_t)snd * 128;
            float* rap = recv_agg + (size_t)rcv * 128;
            const float* erow = e_rw + grow * 128;
            float s1 = 0.f, s2 = 0.f;
            #pragma unroll
            for (int t = 0; t < 8; ++t) {
                int col = t * 16 + c0;
                float en = fmaxf(acc2[t][r] + sB1[col], 0.f);
                atomicAdd(&sap[col], en);
                atomicAdd(&rap[col], en);
                colsum[t] += en;
                float rv = en + erow[col];
                acc2[t][r] = rv;
                s1 += rv;
                s2 += rv * rv;
            }
            #pragma unroll
            for (int off = 1; off < 16; off <<= 1) {
                s1 += __shfl_xor(s1, off, 16);
                s2 += __shfl_xor(s2, off, 16);
            }
            float mean = s1 * (1.f / 128.f);
            float var = s2 * (1.f / 128.f) - mean * mean;
            mean_r[r] = mean;
            rstd_r[r] = rsqrtf(var + LN_EPS);
        }
        #pragma unroll
        for (int r = 0; r < 4; ++r) {
            int rl = w * 16 + (lane >> 4) * 4 + r;
            float* orow = e_rw + (size_t)(rowbase + rl) * 128;
            #pragma unroll
            for (int t = 0; t < 8; ++t) {
                int col = t * 16 + c0;
                orow[col] = (acc2[t][r] - mean_r[r]) * rstd_r[r] * sS[col] + sO[col];
            }
        }
        #pragma unroll
        for (int t = 0; t < 8; ++t) {
            float c = colsum[t];
            c += __shfl_xor(c, 16, 64);
            c += __shfl_xor(c, 32, 64);
            if (lane < 16) sEagg[w][t * 16 + lane] = c;
        }
    }
    __syncthreads();
    if (tid < 128) {
        float v = 0.f;
        #pragma unroll
        for (int ww = 0; ww < 8; ++ww) v += sEagg[ww][tid];
        atomicAdd(&edge_agg[tid], v);
    }
}

// Node update: n_new = relu(relu(n@A + sa@B + ra@C + gvec)@W1 + b1); node_agg; residual+LN.
__global__ __launch_bounds__(256, 2) void k_node(
    float* n_rw, const float* __restrict__ sent_agg, const float* __restrict__ recv_agg,
    float* __restrict__ node_agg, const float* __restrict__ W0, const float* __restrict__ W1,
    const float* __restrict__ gvec, const float* __restrict__ b1,
    const float* __restrict__ lnS, const float* __restrict__ lnO) {
    __shared__ bf16 sW0[128 * 128];
    __shared__ bf16 sW1[128 * 128];
    __shared__ bf16 sX[64 * 128];
    __shared__ float sGv[128], sB1[128], sS[128], sO[128];
    __shared__ float sNagg[4][128];

    const int tid = threadIdx.x;
    const int lane = tid & 63;
    const int w = tid >> 6;
    const int rowbase = blockIdx.x * 64;
    const bool wvalid = (rowbase + w * 16) < NN;
    const int arow = w * 16 + (lane & 15);
    const int kq = (lane >> 4) * 16;
    const int c0 = lane & 15;

    stage_w_t<256>(W1, sW1, tid);
    if (tid < 128) {
        sGv[tid] = gvec[tid];
        sB1[tid] = b1[tid];
        sS[tid] = lnS[tid];
        sO[tid] = lnO[tid];
    }
    for (int i = tid; i < 512; i += 256) (&sNagg[0][0])[i] = 0.f;

    f32x4 acc[8];
    #pragma unroll
    for (int t = 0; t < 8; ++t) acc[t] = f4zero();

    #pragma unroll
    for (int c = 0; c < 3; ++c) {
        __syncthreads();
        stage_w_t<256>(W0 + (size_t)c * 128 * 128, sW0, tid);
        __syncthreads();
        const float* src = (c == 0) ? n_rw : ((c == 1) ? sent_agg : recv_agg);
        if (wvalid) {
            stage_rows16(src + (size_t)(rowbase + w * 16) * 128, sX, w * 16, lane);
            mfma_16x128(sX, sW0, arow, kq, acc);
        }
    }

    if (wvalid) {
        #pragma unroll
        for (int r = 0; r < 4; ++r) {
            int rl = w * 16 + (lane >> 4) * 4 + r;
            #pragma unroll
            for (int t = 0; t < 8; ++t) {
                int col = t * 16 + c0;
                float v = fmaxf(acc[t][r] + sGv[col], 0.f);
                *reinterpret_cast<bf16*>(reinterpret_cast<char*>(sX) + swz_off(rl, col * 2)) = (bf16)v;
            }
        }
    }

    f32x4 acc2[8];
    #pragma unroll
    for (int t = 0; t < 8; ++t) acc2[t] = f4zero();
    if (wvalid) {
        mfma_16x128(sX, sW1, arow, kq, acc2);
        float colsum[8];
        #pragma unroll
        for (int t = 0; t < 8; ++t) colsum[t] = 0.f;
        float mean_r[4], rstd_r[4];
        #pragma unroll
        for (int r = 0; r < 4; ++r) {
            int rl = w * 16 + (lane >> 4) * 4 + r;
            const float* nrow = n_rw + (size_t)(rowbase + rl) * 128;
            float s1 = 0.f, s2 = 0.f;
            #pragma unroll
            for (int t = 0; t < 8; ++t) {
                int col = t * 16 + c0;
                float nn = fmaxf(acc2[t][r] + sB1[col], 0.f);
                colsum[t] += nn;
                float rv = nn + nrow[col];
                acc2[t][r] = rv;
                s1 += rv;
                s2 += rv * rv;
            }
            #pragma unroll
            for (int off = 1; off < 16; off <<= 1) {
                s1 += __shfl_xor(s1, off, 16);
                s2 += __shfl_xor(s2, off, 16);
            }
            float mean = s1 * (1.f / 128.f);
            float var = s2 * (1.f / 128.f) - mean * mean;
            mean_r[r] = mean;
            rstd_r[r] = rsqrtf(var + LN_EPS);
        }
        #pragma unroll
        for (int r = 0; r < 4; ++r) {
            int rl = w * 16 + (lane >> 4) * 4 + r;
            float* orow = n_rw + (size_t)(rowbase + rl) * 128;
            #pragma unroll
            for (int t = 0; t < 8; ++t) {
                int col = t * 16 + c0;
                orow[col] = (acc2[t][r] - mean_r[r]) * rstd_r[r] * sS[col] + sO[col];
            }
        }
        #pragma unroll
        for (int t = 0; t < 8; ++t) {
            float c = colsum[t];
            c += __shfl_xor(c, 16, 64);
            c += __shfl_xor(c, 32, 64);
            if (lane < 16) sNagg[w][t * 16 + lane] = c;
        }
    }
    __syncthreads();
    if (tid < 128) {
        float v = sNagg[0][tid] + sNagg[1][tid] + sNagg[2][tid] + sNagg[3][tid];
        atomicAdd(&node_agg[tid], v);
    }
}

// Global update (1 block, 256 threads) + next-step gvec precompute + optional decode.
__global__ void k_glob(float* __restrict__ g, const float* __restrict__ node_agg,
                       const float* __restrict__ edge_agg, const float* __restrict__ W0,
                       const float* __restrict__ b0, const float* __restrict__ W1,
                       const float* __restrict__ b1, const float* __restrict__ lnS,
                       const float* __restrict__ lnO, const float* __restrict__ eW0g,
                       const float* __restrict__ eb0, const float* __restrict__ nW0g,
                       const float* __restrict__ nb0, float* __restrict__ gvec_e,
                       float* __restrict__ gvec_n, const float* __restrict__ decW,
                       const float* __restrict__ decb, float* __restrict__ out, int do_next,
                       int do_dec) {
    __shared__ float sP[2][128];
    __shared__ float sH[128];
    __shared__ float sG[128];
    __shared__ float sMR[2];
    const int tid = threadIdx.x;
    const int j = tid & 127;
    const int half = tid >> 7;

    float p = 0.f;
    for (int k = 0; k < 64; ++k) {
        int kk = half * 64 + k;
        p += node_agg[kk] * W0[kk * 128 + j];
        p += edge_agg[kk] * W0[(128 + kk) * 128 + j];
        p += g[kk] * W0[(256 + kk) * 128 + j];
    }
    sP[half][j] = p;
    __syncthreads();
    if (half == 0) sH[j] = fmaxf(b0[j] + sP[0][j] + sP[1][j], 0.f);
    __syncthreads();
    p = 0.f;
    for (int k = 0; k < 64; ++k) {
        int kk = half * 64 + k;
        p += sH[kk] * W1[kk * 128 + j];
    }
    sP[half][j] = p;
    __syncthreads();
    float res = 0.f;
    if (half == 0) {
        float gn = fmaxf(b1[j] + sP[0][j] + sP[1][j], 0.f);
        res = gn + g[j];
    }
    __syncthreads();
    if (half == 0) {
        sP[0][j] = res;
        sP[1][j] = res * res;
    }
    __syncthreads();
    if (tid < 64) {
        float a = sP[0][tid] + sP[0][tid + 64];
        float q = sP[1][tid] + sP[1][tid + 64];
        #pragma unroll
        for (int off = 1; off < 64; off <<= 1) {
            a += __shfl_xor(a, off, 64);
            q += __shfl_xor(q, off, 64);
        }
        if (tid == 0) {
            float m = a * (1.f / 128.f);
            float v = q * (1.f / 128.f) - m * m;
            sMR[0] = m;
            sMR[1] = rsqrtf(v + LN_EPS);
        }
    }
    __syncthreads();
    if (half == 0) {
        float go = (res - sMR[0]) * sMR[1] * lnS[j] + lnO[j];
        g[j] = go;
        sG[j] = go;
    }
    __syncthreads();
    if (do_next && half == 0) {
        float ae = eb0[j], an = nb0[j];
        for (int k = 0; k < 128; ++k) {
            float gv = sG[k];
            ae += gv * eW0g[k * 128 + j];
            an += gv * nW0g[k * 128 + j];
        }
        gvec_e[j] = ae;
        gvec_n[j] = an;
    }
    if (do_dec && tid < 8) {
        float a = decb[tid];
        for (int k = 0; k < 128; ++k) a += sG[k] * decW[k * 8 + tid];
        out[tid] = a;
    }
}

extern "C" void kernel_launch(void* const* d_in, const int* in_sizes, int n_in, void* d_out,
                              int out_size, void* d_ws, size_t ws_size, hipStream_t stream) {
    (void)in_sizes; (void)n_in; (void)out_size; (void)ws_size;
    const float* nodes = (const float*)d_in[0];
    const float* edges = (const float*)d_in[1];
    const float* globals_ = (const float*)d_in[2];
    const int* senders = (const int*)d_in[3];
    const int* receivers = (const int*)d_in[4];
    const float* emb_node_W = (const float*)d_in[5];
    const float* emb_node_b = (const float*)d_in[6];
    const float* emb_edge_W = (const float*)d_in[7];
    const float* emb_edge_b = (const float*)d_in[8];
    const float* emb_glob_W = (const float*)d_in[9];
    const float* emb_glob_b = (const float*)d_in[10];
    const float* edge_W0 = (const float*)d_in[11];
    const float* edge_b0 = (const float*)d_in[12];
    const float* edge_W1 = (const float*)d_in[13];
    const float* edge_b1 = (const float*)d_in[14];
    const float* node_W0 = (const float*)d_in[15];
    const float* node_b0 = (const float*)d_in[16];
    const float* node_W1 = (const float*)d_in[17];
    const float* node_b1 = (const float*)d_in[18];
    const float* glob_W0 = (const float*)d_in[19];
    const float* glob_b0 = (const float*)d_in[20];
    const float* glob_W1 = (const float*)d_in[21];
    const float* glob_b1 = (const float*)d_in[22];
    const float* ln_scale = (const float*)d_in[23];
    const float* ln_offset = (const float*)d_in[24];
    const float* dec_W = (const float*)d_in[25];
    const float* dec_b = (const float*)d_in[26];

    char* ws = (char*)d_ws;
    size_t off = 0;
    float* e = (float*)(ws + off);    off += (size_t)NE * NL * 4;
    float* n = (float*)(ws + off);    off += (size_t)NN * NL * 4;
    float* nsW = (float*)(ws + off);  off += (size_t)NN * NL * 4;
    float* nrW = (float*)(ws + off);  off += (size_t)NN * NL * 4;
    float* sent = (float*)(ws + off); off += (size_t)NN * NL * 4;
    float* recv = (float*)(ws + off); off += (size_t)NN * NL * 4;
    float* eagg = (float*)(ws + off); off += 128 * 4;
    float* nagg = (float*)(ws + off); off += 128 * 4;
    float* g = (float*)(ws + off);    off += 128 * 4;
    float* gve = (float*)(ws + off);  off += 128 * 4;
    float* gvn = (float*)(ws + off);  off += 128 * 4;

    const int NB_N = (NN + 63) / 64;  // 157
    const int NB_E = NE / 128;        // 1250

    k_embed_nodes<<<NB_N, 256, 0, stream>>>(nodes, emb_node_W, emb_node_b, n);
    k_embed_edges<<<NB_E, 256, 0, stream>>>(edges, emb_edge_W, emb_edge_b, e);
    k_init_glob<<<1, 128, 0, stream>>>(globals_, emb_glob_W, emb_glob_b, g,
                                       edge_W0 + 384 * 128, edge_b0, node_W0 + 384 * 128,
                                       node_b0, gve, gvn);

    for (int s = 0; s < 3; ++s) {
        hipMemsetAsync(sent, 0, (size_t)(2 * NN * NL + 256) * 4, stream);
        k_proj<<<NB_N, 256, 0, stream>>>(n, nsW, nrW,
                                         edge_W0 + (size_t)s * 512 * 128 + 128 * 128,
                                         edge_W0 + (size_t)s * 512 * 128 + 256 * 128);
        k_edge<<<NB_E, 512, 0, stream>>>(e, nsW, nrW, sent, recv, eagg, senders, receivers,
                                         edge_W0 + (size_t)s * 512 * 128,
                                         edge_W1 + (size_t)s * 128 * 128, gve,
                                         edge_b1 + s * 128, ln_scale + (s * 3 + 1) * 128,
                                         ln_offset + (s * 3 + 1) * 128);
        k_node<<<NB_N, 256, 0, stream>>>(n, sent, recv, nagg,
                                         node_W0 + (size_t)s * 512 * 128,
                                         node_W1 + (size_t)s * 128 * 128, gvn,
                                         node_b1 + s * 128, ln_scale + (s * 3 + 0) * 128,
                                         ln_offset + (s * 3 + 0) * 128);
        const int last = (s == 2);
        const float* eW0g = last ? edge_W0 : edge_W0 + (size_t)(s + 1) * 512 * 128 + 384 * 128;
        const float* eb0n = last ? edge_b0 : edge_b0 + (s + 1) * 128;
        const float* nW0g = last ? node_W0 : node_W0 + (size_t)(s + 1) * 512 * 128 + 384 * 128;
        const float* nb0n = last ? node_b0 : node_b0 + (s + 1) * 128;
        k_glob<<<1, 256, 0, stream>>>(g, nagg, eagg, glob_W0 + (size_t)s * 384 * 128,
                                      glob_b0 + s * 128, glob_W1 + (size_t)s * 128 * 128,
                                      glob_b1 + s * 128, ln_scale + (s * 3 + 2) * 128,
                                      ln_offset + (s * 3 + 2) * 128, eW0g, eb0n, nW0g, nb0n,
                                      gve, gvn, dec_W, dec_b, (float*)d_out, !last, last);
    }
}

// Round 2
// 682.873 us; speedup vs baseline: 1.1277x; 1.1277x over previous
//
#include <hip/hip_runtime.h>
#include <hip/hip_bf16.h>

typedef __bf16 bf16;
typedef __bf16 bf16x8 __attribute__((ext_vector_type(8)));
typedef __bf16 bf16x4 __attribute__((ext_vector_type(4)));
typedef __bf16 bf16x2 __attribute__((ext_vector_type(2)));
typedef float  f32x4  __attribute__((ext_vector_type(4)));
typedef float  f32x2  __attribute__((ext_vector_type(2)));

#define NL 128
#define NN 10000
#define NE 160000
#define LN_EPS 1e-5f

__device__ __forceinline__ f32x4 f4zero() {
    f32x4 v; v[0] = 0.f; v[1] = 0.f; v[2] = 0.f; v[3] = 0.f; return v;
}

// LDS tiles are [row][128] bf16 (256B row stride); byte offset within a row is
// XOR-swizzled by ((row&7)<<4) (T2) to kill the stride-256B ds_read_b128 conflict.
__device__ __forceinline__ int swz_off(int row, int b) {
    return row * 256 + (b ^ ((row & 7) << 4));
}

__device__ __forceinline__ bf16x8 frag_ld(const bf16* base, int row, int kbyte) {
    return *reinterpret_cast<const bf16x8*>(
        reinterpret_cast<const char*>(base) + swz_off(row, kbyte));
}

// Stage W[128][128] f32 row-major (k-major) global -> LDS Wt[col][k] bf16 swizzled.
template <int NT>
__device__ __forceinline__ void stage_w_t(const float* __restrict__ Wg, bf16* sWt, int tid) {
    for (int i = 0; i < 4096 / NT; ++i) {
        int q = tid + i * NT;
        int col = q & 127;
        int k0 = (q >> 7) << 2;
        bf16x4 v;
        v[0] = (bf16)Wg[(k0 + 0) * 128 + col];
        v[1] = (bf16)Wg[(k0 + 1) * 128 + col];
        v[2] = (bf16)Wg[(k0 + 2) * 128 + col];
        v[3] = (bf16)Wg[(k0 + 3) * 128 + col];
        *reinterpret_cast<bf16x4*>(reinterpret_cast<char*>(sWt) + swz_off(col, k0 * 2)) = v;
    }
}

// Stage 16 rows x 128 f32 -> bf16 LDS rows [wrow0 .. wrow0+15], one wave.
__device__ __forceinline__ void stage_rows16(const float* __restrict__ src0, bf16* sX,
                                             int wrow0, int lane) {
    int c8 = (lane & 15) * 8;
    #pragma unroll
    for (int i = 0; i < 4; ++i) {
        int sub = i * 4 + (lane >> 4);
        const float* src = src0 + (size_t)sub * 128 + c8;
        f32x4 a = *reinterpret_cast<const f32x4*>(src);
        f32x4 b = *reinterpret_cast<const f32x4*>(src + 4);
        bf16x8 v;
        v[0] = (bf16)a[0]; v[1] = (bf16)a[1]; v[2] = (bf16)a[2]; v[3] = (bf16)a[3];
        v[4] = (bf16)b[0]; v[5] = (bf16)b[1]; v[6] = (bf16)b[2]; v[7] = (bf16)b[3];
        *reinterpret_cast<bf16x8*>(reinterpret_cast<char*>(sX) + swz_off(wrow0 + sub, c8 * 2)) = v;
    }
}

// Stage 16 rows x 128 bf16 (global) -> LDS, one wave.
__device__ __forceinline__ void stage_rows16_bf16(const bf16* __restrict__ src0, bf16* sX,
                                                  int wrow0, int lane) {
    int c8 = (lane & 15) * 8;
    #pragma unroll
    for (int i = 0; i < 4; ++i) {
        int sub = i * 4 + (lane >> 4);
        bf16x8 v = *reinterpret_cast<const bf16x8*>(src0 + (size_t)sub * 128 + c8);
        *reinterpret_cast<bf16x8*>(reinterpret_cast<char*>(sX) + swz_off(wrow0 + sub, c8 * 2)) = v;
    }
}

// One wave: 16 rows x 128 cols, K=128.
__device__ __forceinline__ void mfma_16x128(const bf16* sA, const bf16* sB, int arow, int kq,
                                            f32x4 acc[8]) {
    #pragma unroll
    for (int kk = 0; kk < 4; ++kk) {
        bf16x8 af = frag_ld(sA, arow, kk * 64 + kq);
        #pragma unroll
        for (int t = 0; t < 8; ++t) {
            bf16x8 bfr = frag_ld(sB, t * 16 + (arow & 15), kk * 64 + kq);
            acc[t] = __builtin_amdgcn_mfma_f32_16x16x32_bf16(af, bfr, acc[t], 0, 0, 0);
        }
    }
}

// Write a wave's C fragments (bf16) into its private sX rows.
__device__ __forceinline__ void acc_to_lds_bf16(bf16* sX, const f32x4 acc[8], int w, int lane) {
    int c0 = lane & 15;
    #pragma unroll
    for (int r = 0; r < 4; ++r) {
        int rl = w * 16 + (lane >> 4) * 4 + r;
        #pragma unroll
        for (int t = 0; t < 8; ++t) {
            int col = t * 16 + c0;
            *reinterpret_cast<bf16*>(reinterpret_cast<char*>(sX) + swz_off(rl, col * 2)) =
                (bf16)acc[t][r];
        }
    }
}

// Coalesced copy of a wave's 16 LDS rows -> global bf16.
__device__ __forceinline__ void lds_rows_to_global_bf16(const bf16* sX, bf16* __restrict__ dst0,
                                                        int w, int lane) {
    int c8 = (lane & 15) * 8;
    #pragma unroll
    for (int i = 0; i < 4; ++i) {
        int sub = i * 4 + (lane >> 4);
        bf16x8 v = *reinterpret_cast<const bf16x8*>(
            reinterpret_cast<const char*>(sX) + swz_off(w * 16 + sub, c8 * 2));
        *reinterpret_cast<bf16x8*>(dst0 + (size_t)sub * 128 + c8) = v;
    }
}

// ---------------- CSR build ----------------

__global__ void k_hist(const int* __restrict__ senders, const int* __restrict__ receivers,
                       int* __restrict__ deg_s, int* __restrict__ deg_r) {
    int i = blockIdx.x * 256 + threadIdx.x;
    if (i < NE) {
        atomicAdd(&deg_s[senders[i]], 1);
        atomicAdd(&deg_r[receivers[i]], 1);
    }
}

__device__ void scan_arr(const int* __restrict__ deg, int* __restrict__ rs, int* __restrict__ cur,
                         int* sW, int* sRun) {
    const int tid = threadIdx.x, lane = tid & 63, wid = tid >> 6;
    if (tid == 0) *sRun = 0;
    __syncthreads();
    for (int base = 0; base < NN; base += 1024) {
        int i = base + tid;
        int orig = (i < NN) ? deg[i] : 0;
        int v = orig;
        #pragma unroll
        for (int off = 1; off < 64; off <<= 1) {
            int u = __shfl_up(v, off, 64);
            if (lane >= off) v += u;
        }
        if (lane == 63) sW[wid] = v;
        __syncthreads();
        if (wid == 0 && lane < 16) {
            int u = sW[lane];
            #pragma unroll
            for (int off = 1; off < 16; off <<= 1) {
                int t = __shfl_up(u, off, 16);
                if (lane >= off) u += t;
            }
            sW[lane] = u;
        }
        __syncthreads();
        int waveoff = (wid == 0) ? 0 : sW[wid - 1];
        int incl = v + waveoff + *sRun;
        if (i < NN) {
            rs[i + 1] = incl;
            cur[i] = incl - orig;
        }
        __syncthreads();
        if (tid == 1023) *sRun = incl;
        __syncthreads();
    }
    if (tid == 0) rs[0] = 0;
}

__global__ void k_scan(const int* __restrict__ deg_s, int* __restrict__ rs_s,
                       int* __restrict__ cur_s, const int* __restrict__ deg_r,
                       int* __restrict__ rs_r, int* __restrict__ cur_r) {
    __shared__ int sW[16];
    __shared__ int sRun;
    scan_arr(deg_s, rs_s, cur_s, sW, &sRun);
    __syncthreads();
    scan_arr(deg_r, rs_r, cur_r, sW, &sRun);
}

__global__ void k_scatter_s(const int* __restrict__ senders, const int* __restrict__ receivers,
                            int* __restrict__ cur_s, int* __restrict__ perm,
                            int* __restrict__ snd_s, int* __restrict__ rcv_s) {
    int i = blockIdx.x * 256 + threadIdx.x;
    if (i < NE) {
        int s = senders[i];
        int p = atomicAdd(&cur_s[s], 1);
        perm[p] = i;
        snd_s[p] = s;
        rcv_s[p] = receivers[i];
    }
}

__global__ void k_scatter_r(const int* __restrict__ rcv_s, int* __restrict__ cur_r,
                            int* __restrict__ csr_r) {
    int j = blockIdx.x * 256 + threadIdx.x;
    if (j < NE) {
        int r = rcv_s[j];
        int p = atomicAdd(&cur_r[r], 1);
        csr_r[p] = j;
    }
}

// ---------------- embed ----------------

__global__ void k_embed_nodes(const float* __restrict__ nodes, const float* __restrict__ W,
                              const float* __restrict__ b, float* __restrict__ n_out) {
    __shared__ float sW[64 * 128];
    __shared__ float sB[128];
    const int tid = threadIdx.x;
    for (int i = tid; i < 64 * 128; i += 256) sW[i] = W[i];
    if (tid < 128) sB[tid] = b[tid];
    __syncthreads();
    const int col = tid & 127;
    const int rh = tid >> 7;
    const int rowbase = blockIdx.x * 64;
    for (int i = 0; i < 32; ++i) {
        int row = rowbase + i * 2 + rh;
        if (row < NN) {
            const f32x4* x4 = reinterpret_cast<const f32x4*>(nodes + (size_t)row * 64);
            float a = sB[col];
            #pragma unroll
            for (int k4 = 0; k4 < 16; ++k4) {
                f32x4 xv = x4[k4];
                a += xv[0] * sW[(k4 * 4 + 0) * 128 + col];
                a += xv[1] * sW[(k4 * 4 + 1) * 128 + col];
                a += xv[2] * sW[(k4 * 4 + 2) * 128 + col];
                a += xv[3] * sW[(k4 * 4 + 3) * 128 + col];
            }
            n_out[(size_t)row * 128 + col] = a;
        }
    }
}

// Embeds edges[perm[j]] -> e[j] (bf16), applying the sender-sort permutation.
__global__ void k_embed_edges(const float* __restrict__ edges, const int* __restrict__ perm,
                              const float* __restrict__ W, const float* __restrict__ b,
                              bf16* __restrict__ e_out) {
    __shared__ float sW[16 * 128];
    __shared__ float sB[128];
    const int tid = threadIdx.x;
    for (int i = tid; i < 16 * 128; i += 256) sW[i] = W[i];
    if (tid < 128) sB[tid] = b[tid];
    __syncthreads();
    const int col = tid & 127;
    const int rh = tid >> 7;
    const int rowbase = blockIdx.x * 128;
    for (int i = 0; i < 64; ++i) {
        int row = rowbase + i * 2 + rh;
        int src = perm[row];
        const float* x = edges + (size_t)src * 16;
        float a = sB[col];
        #pragma unroll
        for (int k = 0; k < 16; ++k) a += x[k] * sW[k * 128 + col];
        e_out[(size_t)row * 128 + col] = (bf16)a;
    }
}

__global__ void k_init_glob(const float* __restrict__ globals_, const float* __restrict__ embW,
                            const float* __restrict__ embB, float* __restrict__ g,
                            const float* __restrict__ eW0g, const float* __restrict__ eb0,
                            const float* __restrict__ nW0g, const float* __restrict__ nb0,
                            float* __restrict__ gvec_e, float* __restrict__ gvec_n,
                            float* __restrict__ eagg, float* __restrict__ nagg) {
    __shared__ float sG[128];
    const int tid = threadIdx.x;  // 128 threads
    float a = embB[tid];
    #pragma unroll
    for (int k = 0; k < 8; ++k) a += globals_[k] * embW[k * 128 + tid];
    g[tid] = a;
    sG[tid] = a;
    eagg[tid] = 0.f;
    nagg[tid] = 0.f;
    __syncthreads();
    float ae = eb0[tid], an = nb0[tid];
    for (int k = 0; k < 128; ++k) {
        float gv = sG[k];
        ae += gv * eW0g[k * 128 + tid];
        an += gv * nW0g[k * 128 + tid];
    }
    gvec_e[tid] = ae;
    gvec_n[tid] = an;
}

// ---------------- per-step kernels ----------------

// nsW = (bf16)(n @ W0b),  nrW = (bf16)(n @ W0c)
__global__ __launch_bounds__(256, 2) void k_proj(const float* __restrict__ n_in,
                                                 bf16* __restrict__ nsW, bf16* __restrict__ nrW,
                                                 const float* __restrict__ Wns,
                                                 const float* __restrict__ Wnr) {
    __shared__ char smem[81920];
    bf16* sWa = (bf16*)smem;
    bf16* sWb = (bf16*)(smem + 32768);
    bf16* sX = (bf16*)(smem + 65536);
    const int tid = threadIdx.x;
    const int lane = tid & 63;
    const int w = tid >> 6;
    const int rowbase = blockIdx.x * 64;
    const bool wvalid = (rowbase + w * 16) < NN;

    stage_w_t<256>(Wns, sWa, tid);
    stage_w_t<256>(Wnr, sWb, tid);
    if (wvalid) stage_rows16(n_in + (size_t)(rowbase + w * 16) * 128, sX, w * 16, lane);
    __syncthreads();
    if (!wvalid) return;

    const int arow = w * 16 + (lane & 15);
    const int kq = (lane >> 4) * 16;
    f32x4 acc[8], acc2[8];
    #pragma unroll
    for (int t = 0; t < 8; ++t) { acc[t] = f4zero(); acc2[t] = f4zero(); }
    mfma_16x128(sX, sWa, arow, kq, acc);
    mfma_16x128(sX, sWb, arow, kq, acc2);

    acc_to_lds_bf16(sX, acc, w, lane);
    lds_rows_to_global_bf16(sX, nsW + (size_t)(rowbase + w * 16) * 128, w, lane);
    acc_to_lds_bf16(sX, acc2, w, lane);
    lds_rows_to_global_bf16(sX, nrW + (size_t)(rowbase + w * 16) * 128, w, lane);
}

// Edge update, no scatter atomics: writes e_new (bf16) and e = LN(e_new + e_old) (bf16).
__global__ __launch_bounds__(256, 2) void k_edge(
    bf16* e_rw, bf16* __restrict__ e_new_out, const bf16* __restrict__ nsW,
    const bf16* __restrict__ nrW, float* __restrict__ edge_agg,
    const int* __restrict__ snd_s, const int* __restrict__ rcv_s,
    const float* __restrict__ W0a, const float* __restrict__ W1,
    const float* __restrict__ gvec, const float* __restrict__ b1,
    const float* __restrict__ lnS, const float* __restrict__ lnO) {
    __shared__ char smem[81920];
    bf16* sW0 = (bf16*)smem;
    bf16* sW1 = (bf16*)(smem + 32768);
    bf16* sX = (bf16*)(smem + 65536);
    float* sEagg = (float*)(smem + 65536);  // alias; used after barrier

    const int tid = threadIdx.x;
    const int lane = tid & 63;
    const int w = tid >> 6;  // 0..3
    const int rowbase = blockIdx.x * 64;
    const int arow = w * 16 + (lane & 15);
    const int kq = (lane >> 4) * 16;
    const int c0 = lane & 15;

    stage_w_t<256>(W0a, sW0, tid);
    stage_w_t<256>(W1, sW1, tid);
    __syncthreads();
    stage_rows16_bf16(e_rw + (size_t)(rowbase + w * 16) * 128, sX, w * 16, lane);

    // layer 0
    f32x4 acc[8];
    #pragma unroll
    for (int t = 0; t < 8; ++t) acc[t] = f4zero();
    mfma_16x128(sX, sW0, arow, kq, acc);

    // grab e_old fragments + indices before sX is overwritten
    int rl_r[4], snd_r[4], rcv_r[4];
    float eold[4][8];
    #pragma unroll
    for (int r = 0; r < 4; ++r) {
        int rl = w * 16 + (lane >> 4) * 4 + r;
        rl_r[r] = rl;
        snd_r[r] = snd_s[rowbase + rl];
        rcv_r[r] = rcv_s[rowbase + rl];
        #pragma unroll
        for (int t = 0; t < 8; ++t) {
            int col = t * 16 + c0;
            eold[r][t] = (float)(*reinterpret_cast<const bf16*>(
                reinterpret_cast<const char*>(sX) + swz_off(rl, col * 2)));
        }
    }
    float gv[8], bb[8], ls[8], lo[8];
    #pragma unroll
    for (int t = 0; t < 8; ++t) {
        int col = t * 16 + c0;
        gv[t] = gvec[col]; bb[t] = b1[col]; ls[t] = lnS[col]; lo[t] = lnO[col];
    }

    // fixup: h = relu(acc + nsW[snd] + nrW[rcv] + gvec) -> sX (wave-private rows)
    #pragma unroll
    for (int r = 0; r < 4; ++r) {
        const bf16* nsp = nsW + (size_t)snd_r[r] * 128;
        const bf16* nrp = nrW + (size_t)rcv_r[r] * 128;
        #pragma unroll
        for (int t = 0; t < 8; ++t) {
            int col = t * 16 + c0;
            float v = acc[t][r] + (float)nsp[col] + (float)nrp[col] + gv[t];
            v = fmaxf(v, 0.f);
            *reinterpret_cast<bf16*>(reinterpret_cast<char*>(sX) + swz_off(rl_r[r], col * 2)) =
                (bf16)v;
        }
    }

    // layer 1
    f32x4 acc2[8];
    #pragma unroll
    for (int t = 0; t < 8; ++t) acc2[t] = f4zero();
    mfma_16x128(sX, sW1, arow, kq, acc2);

    // epilogue: e_new = relu(acc2 + b1); colsum; residual + LN stats
    float colsum[8];
    #pragma unroll
    for (int t = 0; t < 8; ++t) colsum[t] = 0.f;
    float mean_r[4], rstd_r[4];
    #pragma unroll
    for (int r = 0; r < 4; ++r) {
        float s1 = 0.f, s2 = 0.f;
        #pragma unroll
        for (int t = 0; t < 8; ++t) {
            int col = t * 16 + c0;
            float en = fmaxf(acc2[t][r] + bb[t], 0.f);
            colsum[t] += en;
            *reinterpret_cast<bf16*>(reinterpret_cast<char*>(sX) + swz_off(rl_r[r], col * 2)) =
                (bf16)en;
            float rv = en + eold[r][t];
            acc2[t][r] = rv;
            s1 += rv;
            s2 += rv * rv;
        }
        #pragma unroll
        for (int off = 1; off < 16; off <<= 1) {
            s1 += __shfl_xor(s1, off, 16);
            s2 += __shfl_xor(s2, off, 16);
        }
        float mean = s1 * (1.f / 128.f);
        float var = s2 * (1.f / 128.f) - mean * mean;
        mean_r[r] = mean;
        rstd_r[r] = rsqrtf(var + LN_EPS);
    }
    // coalesced e_new write
    lds_rows_to_global_bf16(sX, e_new_out + (size_t)(rowbase + w * 16) * 128, w, lane);
    // LN output -> sX -> coalesced e write
    #pragma unroll
    for (int r = 0; r < 4; ++r) {
        #pragma unroll
        for (int t = 0; t < 8; ++t) {
            int col = t * 16 + c0;
            float val = (acc2[t][r] - mean_r[r]) * rstd_r[r] * ls[t] + lo[t];
            *reinterpret_cast<bf16*>(reinterpret_cast<char*>(sX) + swz_off(rl_r[r], col * 2)) =
                (bf16)val;
        }
    }
    lds_rows_to_global_bf16(sX, e_rw + (size_t)(rowbase + w * 16) * 128, w, lane);

    // block edge_agg reduction (tiny atomic count)
    __syncthreads();
    #pragma unroll
    for (int t = 0; t < 8; ++t) {
        float c = colsum[t];
        c += __shfl_xor(c, 16, 64);
        c += __shfl_xor(c, 32, 64);
        if (lane < 16) sEagg[w * 128 + t * 16 + lane] = c;
    }
    __syncthreads();
    if (tid < 128) {
        float v = sEagg[tid] + sEagg[128 + tid] + sEagg[256 + tid] + sEagg[384 + tid];
        atomicAdd(&edge_agg[tid], v);
    }
}

// Two-sided aggregation: sent (contiguous segments, sender-sorted) + recv (CSR gather).
__global__ __launch_bounds__(256) void k_agg(const bf16* __restrict__ e_new,
                                             const int* __restrict__ rs_s,
                                             const int* __restrict__ rs_r,
                                             const int* __restrict__ csr_r,
                                             float* __restrict__ sent, float* __restrict__ recv) {
    const int lane = threadIdx.x & 63;
    const int w = threadIdx.x >> 6;
    const int node = blockIdx.x * 4 + w;
    if (node >= NN) return;
    const int co = lane * 2;
    float a0 = 0.f, a1 = 0.f;
    const int b0 = rs_s[node], b1 = rs_s[node + 1];
    for (int j = b0; j < b1; ++j) {
        bf16x2 v = *reinterpret_cast<const bf16x2*>(e_new + (size_t)j * 128 + co);
        a0 += (float)v[0];
        a1 += (float)v[1];
    }
    f32x2 o; o[0] = a0; o[1] = a1;
    *reinterpret_cast<f32x2*>(sent + (size_t)node * 128 + co) = o;
    a0 = 0.f; a1 = 0.f;
    const int c1 = rs_r[node], c2 = rs_r[node + 1];
    for (int p = c1; p < c2; ++p) {
        int j = csr_r[p];
        bf16x2 v = *reinterpret_cast<const bf16x2*>(e_new + (size_t)j * 128 + co);
        a0 += (float)v[0];
        a1 += (float)v[1];
    }
    o[0] = a0; o[1] = a1;
    *reinterpret_cast<f32x2*>(recv + (size_t)node * 128 + co) = o;
}

// Node update: n = LN(relu(relu(n@A + sa@B + ra@C + gvec)@W1 + b1) + n)
__global__ __launch_bounds__(256, 2) void k_node(
    float* n_rw, const float* __restrict__ sent_agg, const float* __restrict__ recv_agg,
    float* __restrict__ node_agg, const float* __restrict__ W0, const float* __restrict__ W1,
    const float* __restrict__ gvec, const float* __restrict__ b1,
    const float* __restrict__ lnS, const float* __restrict__ lnO) {
    __shared__ char smem[81920];
    bf16* sW0 = (bf16*)smem;
    bf16* sW1 = (bf16*)(smem + 32768);
    bf16* sX = (bf16*)(smem + 65536);
    float* sNagg = (float*)(smem + 65536);  // alias; used after barrier

    const int tid = threadIdx.x;
    const int lane = tid & 63;
    const int w = tid >> 6;
    const int rowbase = blockIdx.x * 64;
    const bool wvalid = (rowbase + w * 16) < NN;
    const int arow = w * 16 + (lane & 15);
    const int kq = (lane >> 4) * 16;
    const int c0 = lane & 15;

    stage_w_t<256>(W1, sW1, tid);

    f32x4 acc[8];
    #pragma unroll
    for (int t = 0; t < 8; ++t) acc[t] = f4zero();

    #pragma unroll
    for (int c = 0; c < 3; ++c) {
        __syncthreads();
        stage_w_t<256>(W0 + (size_t)c * 128 * 128, sW0, tid);
        __syncthreads();
        const float* src = (c == 0) ? n_rw : ((c == 1) ? sent_agg : recv_agg);
        if (wvalid) {
            stage_rows16(src + (size_t)(rowbase + w * 16) * 128, sX, w * 16, lane);
            mfma_16x128(sX, sW0, arow, kq, acc);
        }
    }

    float gv[8], bb[8], ls[8], lo[8];
    #pragma unroll
    for (int t = 0; t < 8; ++t) {
        int col = t * 16 + c0;
        gv[t] = gvec[col]; bb[t] = b1[col]; ls[t] = lnS[col]; lo[t] = lnO[col];
    }

    if (wvalid) {
        #pragma unroll
        for (int r = 0; r < 4; ++r) {
            int rl = w * 16 + (lane >> 4) * 4 + r;
            #pragma unroll
            for (int t = 0; t < 8; ++t) {
                int col = t * 16 + c0;
                float v = fmaxf(acc[t][r] + gv[t], 0.f);
                *reinterpret_cast<bf16*>(reinterpret_cast<char*>(sX) + swz_off(rl, col * 2)) =
                    (bf16)v;
            }
        }
    }

    f32x4 acc2[8];
    #pragma unroll
    for (int t = 0; t < 8; ++t) acc2[t] = f4zero();
    float colsum[8];
    #pragma unroll
    for (int t = 0; t < 8; ++t) colsum[t] = 0.f;
    if (wvalid) {
        mfma_16x128(sX, sW1, arow, kq, acc2);
        float mean_r[4], rstd_r[4];
        #pragma unroll
        for (int r = 0; r < 4; ++r) {
            int rl = w * 16 + (lane >> 4) * 4 + r;
            const float* nrow = n_rw + (size_t)(rowbase + rl) * 128;
            float s1 = 0.f, s2 = 0.f;
            #pragma unroll
            for (int t = 0; t < 8; ++t) {
                int col = t * 16 + c0;
                float nn = fmaxf(acc2[t][r] + bb[t], 0.f);
                colsum[t] += nn;
                float rv = nn + nrow[col];
                acc2[t][r] = rv;
                s1 += rv;
                s2 += rv * rv;
            }
            #pragma unroll
            for (int off = 1; off < 16; off <<= 1) {
                s1 += __shfl_xor(s1, off, 16);
                s2 += __shfl_xor(s2, off, 16);
            }
            float mean = s1 * (1.f / 128.f);
            float var = s2 * (1.f / 128.f) - mean * mean;
            mean_r[r] = mean;
            rstd_r[r] = rsqrtf(var + LN_EPS);
        }
        #pragma unroll
        for (int r = 0; r < 4; ++r) {
            int rl = w * 16 + (lane >> 4) * 4 + r;
            float* orow = n_rw + (size_t)(rowbase + rl) * 128;
            #pragma unroll
            for (int t = 0; t < 8; ++t) {
                int col = t * 16 + c0;
                orow[col] = (acc2[t][r] - mean_r[r]) * rstd_r[r] * ls[t] + lo[t];
            }
        }
    }
    __syncthreads();
    #pragma unroll
    for (int t = 0; t < 8; ++t) {
        float c = colsum[t];
        c += __shfl_xor(c, 16, 64);
        c += __shfl_xor(c, 32, 64);
        if (lane < 16) sNagg[w * 128 + t * 16 + lane] = wvalid ? c : 0.f;
    }
    __syncthreads();
    if (tid < 128) {
        float v = sNagg[tid] + sNagg[128 + tid] + sNagg[256 + tid] + sNagg[384 + tid];
        atomicAdd(&node_agg[tid], v);
    }
}

// Global update (1 block, 256 threads) + next-step gvec + agg re-zero + optional decode.
__global__ void k_glob(float* __restrict__ g, float* __restrict__ node_agg,
                       float* __restrict__ edge_agg, const float* __restrict__ W0,
                       const float* __restrict__ b0, const float* __restrict__ W1,
                       const float* __restrict__ b1, const float* __restrict__ lnS,
                       const float* __restrict__ lnO, const float* __restrict__ eW0g,
                       const float* __restrict__ eb0, const float* __restrict__ nW0g,
                       const float* __restrict__ nb0, float* __restrict__ gvec_e,
                       float* __restrict__ gvec_n, const float* __restrict__ decW,
                       const float* __restrict__ decb, float* __restrict__ out, int do_next,
                       int do_dec) {
    __shared__ float sP[2][128];
    __shared__ float sH[128];
    __shared__ float sG[128];
    __shared__ float sMR[2];
    const int tid = threadIdx.x;
    const int j = tid & 127;
    const int half = tid >> 7;

    float p = 0.f;
    for (int k = 0; k < 64; ++k) {
        int kk = half * 64 + k;
        p += node_agg[kk] * W0[kk * 128 + j];
        p += edge_agg[kk] * W0[(128 + kk) * 128 + j];
        p += g[kk] * W0[(256 + kk) * 128 + j];
    }
    sP[half][j] = p;
    __syncthreads();
    if (tid < 128) {  // re-zero aggregates for the next step
        node_agg[tid] = 0.f;
        edge_agg[tid] = 0.f;
    }
    if (half == 0) sH[j] = fmaxf(b0[j] + sP[0][j] + sP[1][j], 0.f);
    __syncthreads();
    p = 0.f;
    for (int k = 0; k < 64; ++k) {
        int kk = half * 64 + k;
        p += sH[kk] * W1[kk * 128 + j];
    }
    sP[half][j] = p;
    __syncthreads();
    float res = 0.f;
    if (half == 0) {
        float gn = fmaxf(b1[j] + sP[0][j] + sP[1][j], 0.f);
        res = gn + g[j];
    }
    __syncthreads();
    if (half == 0) {
        sP[0][j] = res;
        sP[1][j] = res * res;
    }
    __syncthreads();
    if (tid < 64) {
        float a = sP[0][tid] + sP[0][tid + 64];
        float q = sP[1][tid] + sP[1][tid + 64];
        #pragma unroll
        for (int off = 1; off < 64; off <<= 1) {
            a += __shfl_xor(a, off, 64);
            q += __shfl_xor(q, off, 64);
        }
        if (tid == 0) {
            float m = a * (1.f / 128.f);
            float v = q * (1.f / 128.f) - m * m;
            sMR[0] = m;
            sMR[1] = rsqrtf(v + LN_EPS);
        }
    }
    __syncthreads();
    if (half == 0) {
        float go = (res - sMR[0]) * sMR[1] * lnS[j] + lnO[j];
        g[j] = go;
        sG[j] = go;
    }
    __syncthreads();
    if (do_next && half == 0) {
        float ae = eb0[j], an = nb0[j];
        for (int k = 0; k < 128; ++k) {
            float gv = sG[k];
            ae += gv * eW0g[k * 128 + j];
            an += gv * nW0g[k * 128 + j];
        }
        gvec_e[j] = ae;
        gvec_n[j] = an;
    }
    if (do_dec && tid < 8) {
        float a = decb[tid];
        for (int k = 0; k < 128; ++k) a += sG[k] * decW[k * 8 + tid];
        out[tid] = a;
    }
}

extern "C" void kernel_launch(void* const* d_in, const int* in_sizes, int n_in, void* d_out,
                              int out_size, void* d_ws, size_t ws_size, hipStream_t stream) {
    (void)in_sizes; (void)n_in; (void)out_size; (void)ws_size;
    const float* nodes = (const float*)d_in[0];
    const float* edges = (const float*)d_in[1];
    const float* globals_ = (const float*)d_in[2];
    const int* senders = (const int*)d_in[3];
    const int* receivers = (const int*)d_in[4];
    const float* emb_node_W = (const float*)d_in[5];
    const float* emb_node_b = (const float*)d_in[6];
    const float* emb_edge_W = (const float*)d_in[7];
    const float* emb_edge_b = (const float*)d_in[8];
    const float* emb_glob_W = (const float*)d_in[9];
    const float* emb_glob_b = (const float*)d_in[10];
    const float* edge_W0 = (const float*)d_in[11];
    const float* edge_b0 = (const float*)d_in[12];
    const float* edge_W1 = (const float*)d_in[13];
    const float* edge_b1 = (const float*)d_in[14];
    const float* node_W0 = (const float*)d_in[15];
    const float* node_b0 = (const float*)d_in[16];
    const float* node_W1 = (const float*)d_in[17];
    const float* node_b1 = (const float*)d_in[18];
    const float* glob_W0 = (const float*)d_in[19];
    const float* glob_b0 = (const float*)d_in[20];
    const float* glob_W1 = (const float*)d_in[21];
    const float* glob_b1 = (const float*)d_in[22];
    const float* ln_scale = (const float*)d_in[23];
    const float* ln_offset = (const float*)d_in[24];
    const float* dec_W = (const float*)d_in[25];
    const float* dec_b = (const float*)d_in[26];

    char* ws = (char*)d_ws;
    size_t off = 0;
    auto alloc = [&](size_t bytes) -> char* {
        char* p = ws + off;
        off += (bytes + 255) & ~(size_t)255;
        return p;
    };
    bf16* e = (bf16*)alloc((size_t)NE * NL * 2);
    bf16* e_new = (bf16*)alloc((size_t)NE * NL * 2);
    float* n = (float*)alloc((size_t)NN * NL * 4);
    bf16* nsW = (bf16*)alloc((size_t)NN * NL * 2);
    bf16* nrW = (bf16*)alloc((size_t)NN * NL * 2);
    float* sent = (float*)alloc((size_t)NN * NL * 4);
    float* recv = (float*)alloc((size_t)NN * NL * 4);
    float* eagg = (float*)alloc(128 * 4);
    float* nagg = (float*)alloc(128 * 4);
    float* g = (float*)alloc(128 * 4);
    float* gve = (float*)alloc(128 * 4);
    float* gvn = (float*)alloc(128 * 4);
    int* deg = (int*)alloc((size_t)2 * NN * 4);  // deg_s | deg_r contiguous
    int* deg_s = deg;
    int* deg_r = deg + NN;
    int* rs_s = (int*)alloc((size_t)(NN + 1) * 4);
    int* rs_r = (int*)alloc((size_t)(NN + 1) * 4);
    int* cur_s = (int*)alloc((size_t)NN * 4);
    int* cur_r = (int*)alloc((size_t)NN * 4);
    int* perm = (int*)alloc((size_t)NE * 4);
    int* snd_s = (int*)alloc((size_t)NE * 4);
    int* rcv_s = (int*)alloc((size_t)NE * 4);
    int* csr_r = (int*)alloc((size_t)NE * 4);

    const int NB_N = (NN + 63) / 64;   // 157
    const int NB_E = NE / 64;          // 2500
    const int NB_EMB = NE / 128;       // 1250
    const int NB_SC = (NE + 255) / 256;  // 625
    const int NB_AGG = (NN + 3) / 4;   // 2500

    // CSR build (per call; atomic within-segment order only perturbs fp rounding)
    hipMemsetAsync(deg, 0, (size_t)2 * NN * 4, stream);
    k_hist<<<NB_SC, 256, 0, stream>>>(senders, receivers, deg_s, deg_r);
    k_scan<<<1, 1024, 0, stream>>>(deg_s, rs_s, cur_s, deg_r, rs_r, cur_r);
    k_scatter_s<<<NB_SC, 256, 0, stream>>>(senders, receivers, cur_s, perm, snd_s, rcv_s);
    k_scatter_r<<<NB_SC, 256, 0, stream>>>(rcv_s, cur_r, csr_r);

    k_embed_nodes<<<NB_N, 256, 0, stream>>>(nodes, emb_node_W, emb_node_b, n);
    k_embed_edges<<<NB_EMB, 256, 0, stream>>>(edges, perm, emb_edge_W, emb_edge_b, e);
    k_init_glob<<<1, 128, 0, stream>>>(globals_, emb_glob_W, emb_glob_b, g,
                                       edge_W0 + 384 * 128, edge_b0, node_W0 + 384 * 128,
                                       node_b0, gve, gvn, eagg, nagg);

    for (int s = 0; s < 3; ++s) {
        k_proj<<<NB_N, 256, 0, stream>>>(n, nsW, nrW,
                                         edge_W0 + (size_t)s * 512 * 128 + 128 * 128,
                                         edge_W0 + (size_t)s * 512 * 128 + 256 * 128);
        k_edge<<<NB_E, 256, 0, stream>>>(e, e_new, nsW, nrW, eagg, snd_s, rcv_s,
                                         edge_W0 + (size_t)s * 512 * 128,
                                         edge_W1 + (size_t)s * 128 * 128, gve,
                                         edge_b1 + s * 128, ln_scale + (s * 3 + 1) * 128,
                                         ln_offset + (s * 3 + 1) * 128);
        k_agg<<<NB_AGG, 256, 0, stream>>>(e_new, rs_s, rs_r, csr_r, sent, recv);
        k_node<<<NB_N, 256, 0, stream>>>(n, sent, recv, nagg,
                                         node_W0 + (size_t)s * 512 * 128,
                                         node_W1 + (size_t)s * 128 * 128, gvn,
                                         node_b1 + s * 128, ln_scale + (s * 3 + 0) * 128,
                                         ln_offset + (s * 3 + 0) * 128);
        const int last = (s == 2);
        const float* eW0g = last ? edge_W0 : edge_W0 + (size_t)(s + 1) * 512 * 128 + 384 * 128;
        const float* eb0n = last ? edge_b0 : edge_b0 + (s + 1) * 128;
        const float* nW0g = last ? node_W0 : node_W0 + (size_t)(s + 1) * 512 * 128 + 384 * 128;
        const float* nb0n = last ? node_b0 : node_b0 + (s + 1) * 128;
        k_glob<<<1, 256, 0, stream>>>(g, nagg, eagg, glob_W0 + (size_t)s * 384 * 128,
                                      glob_b0 + s * 128, glob_W1 + (size_t)s * 128 * 128,
                                      glob_b1 + s * 128, ln_scale + (s * 3 + 2) * 128,
                                      ln_offset + (s * 3 + 2) * 128, eW0g, eb0n, nW0g, nb0n,
                                      gve, gvn, dec_W, dec_b, (float*)d_out, !last, last);
    }
}

// Round 3
// 606.096 us; speedup vs baseline: 1.2706x; 1.1267x over previous
//
#include <hip/hip_runtime.h>
#include <hip/hip_bf16.h>

typedef __bf16 bf16;
typedef __bf16 bf16x8 __attribute__((ext_vector_type(8)));
typedef __bf16 bf16x4 __attribute__((ext_vector_type(4)));
typedef float  f32x4  __attribute__((ext_vector_type(4)));

#define NL 128
#define NN 10000
#define NE 160000
#define LN_EPS 1e-5f

__device__ __forceinline__ f32x4 f4zero() {
    f32x4 v; v[0] = 0.f; v[1] = 0.f; v[2] = 0.f; v[3] = 0.f; return v;
}

// LDS tiles are [row][128] bf16 (256B row stride); byte offset within a row is
// XOR-swizzled by ((row&7)<<4) (T2) to kill the stride-256B ds_read_b128 conflict.
__device__ __forceinline__ int swz_off(int row, int b) {
    return row * 256 + (b ^ ((row & 7) << 4));
}

__device__ __forceinline__ bf16x8 frag_ld(const bf16* base, int row, int kbyte) {
    return *reinterpret_cast<const bf16x8*>(
        reinterpret_cast<const char*>(base) + swz_off(row, kbyte));
}

// Copy a pre-swizzled 32 KB bf16 weight image global -> LDS (256 threads, 16B/lane).
__device__ __forceinline__ void stage_img(const bf16* __restrict__ img, bf16* dst, int tid) {
    #pragma unroll
    for (int i = 0; i < 8; ++i) {
        int byte = (i * 256 + tid) * 16;
        *reinterpret_cast<bf16x8*>(reinterpret_cast<char*>(dst) + byte) =
            *reinterpret_cast<const bf16x8*>(reinterpret_cast<const char*>(img) + byte);
    }
}

// Stage 16 rows x 128 f32 -> bf16 LDS rows [wrow0 .. wrow0+15], one wave.
__device__ __forceinline__ void stage_rows16(const float* __restrict__ src0, bf16* sX,
                                             int wrow0, int lane) {
    int c8 = (lane & 15) * 8;
    #pragma unroll
    for (int i = 0; i < 4; ++i) {
        int sub = i * 4 + (lane >> 4);
        const float* src = src0 + (size_t)sub * 128 + c8;
        f32x4 a = *reinterpret_cast<const f32x4*>(src);
        f32x4 b = *reinterpret_cast<const f32x4*>(src + 4);
        bf16x8 v;
        v[0] = (bf16)a[0]; v[1] = (bf16)a[1]; v[2] = (bf16)a[2]; v[3] = (bf16)a[3];
        v[4] = (bf16)b[0]; v[5] = (bf16)b[1]; v[6] = (bf16)b[2]; v[7] = (bf16)b[3];
        *reinterpret_cast<bf16x8*>(reinterpret_cast<char*>(sX) + swz_off(wrow0 + sub, c8 * 2)) = v;
    }
}

// Stage 16 rows x 128 bf16 (global) -> LDS, one wave.
__device__ __forceinline__ void stage_rows16_bf16(const bf16* __restrict__ src0, bf16* sX,
                                                  int wrow0, int lane) {
    int c8 = (lane & 15) * 8;
    #pragma unroll
    for (int i = 0; i < 4; ++i) {
        int sub = i * 4 + (lane >> 4);
        bf16x8 v = *reinterpret_cast<const bf16x8*>(src0 + (size_t)sub * 128 + c8);
        *reinterpret_cast<bf16x8*>(reinterpret_cast<char*>(sX) + swz_off(wrow0 + sub, c8 * 2)) = v;
    }
}

// One wave: 16 rows x 128 cols, K=128.
__device__ __forceinline__ void mfma_16x128(const bf16* sA, const bf16* sB, int arow, int kq,
                                            f32x4 acc[8]) {
    #pragma unroll
    for (int kk = 0; kk < 4; ++kk) {
        bf16x8 af = frag_ld(sA, arow, kk * 64 + kq);
        #pragma unroll
        for (int t = 0; t < 8; ++t) {
            bf16x8 bfr = frag_ld(sB, t * 16 + (arow & 15), kk * 64 + kq);
            acc[t] = __builtin_amdgcn_mfma_f32_16x16x32_bf16(af, bfr, acc[t], 0, 0, 0);
        }
    }
}

// Write a wave's C fragments (bf16) into its private sX rows.
__device__ __forceinline__ void acc_to_lds_bf16(bf16* sX, const f32x4 acc[8], int w, int lane) {
    int c0 = lane & 15;
    #pragma unroll
    for (int r = 0; r < 4; ++r) {
        int rl = w * 16 + (lane >> 4) * 4 + r;
        #pragma unroll
        for (int t = 0; t < 8; ++t) {
            int col = t * 16 + c0;
            *reinterpret_cast<bf16*>(reinterpret_cast<char*>(sX) + swz_off(rl, col * 2)) =
                (bf16)acc[t][r];
        }
    }
}

// Coalesced copy of a wave's 16 LDS rows -> global bf16.
__device__ __forceinline__ void lds_rows_to_global_bf16(const bf16* sX, bf16* __restrict__ dst0,
                                                        int w, int lane) {
    int c8 = (lane & 15) * 8;
    #pragma unroll
    for (int i = 0; i < 4; ++i) {
        int sub = i * 4 + (lane >> 4);
        bf16x8 v = *reinterpret_cast<const bf16x8*>(
            reinterpret_cast<const char*>(sX) + swz_off(w * 16 + sub, c8 * 2));
        *reinterpret_cast<bf16x8*>(dst0 + (size_t)sub * 128 + c8) = v;
    }
}

// ---------------- weight image prep ----------------
// 24 images of 128x128 bf16 in LDS-swizzled layout: per step s (0..2), kinds:
// 0:edge W0a  1:edge W0b(proj ns)  2:edge W0c(proj nr)  3:edge W1
// 4:node W0a  5:node W0b           6:node W0c           7:node W1
__global__ void k_prep(const float* __restrict__ eW0, const float* __restrict__ eW1,
                       const float* __restrict__ nW0, const float* __restrict__ nW1,
                       bf16* __restrict__ imgs) {
    const int b = blockIdx.x;  // 24
    const int s = b >> 3, kind = b & 7;
    const float* src;
    if (kind < 3)       src = eW0 + (size_t)s * 512 * 128 + (size_t)kind * 128 * 128;
    else if (kind == 3) src = eW1 + (size_t)s * 128 * 128;
    else if (kind < 7)  src = nW0 + (size_t)s * 512 * 128 + (size_t)(kind - 4) * 128 * 128;
    else                src = nW1 + (size_t)s * 128 * 128;
    bf16* img = imgs + (size_t)b * 16384;
    const int tid = threadIdx.x;
    for (int i = 0; i < 16; ++i) {
        int q = tid + i * 256;
        int col = q & 127;
        int k0 = (q >> 7) << 2;
        bf16x4 v;
        v[0] = (bf16)src[(k0 + 0) * 128 + col];
        v[1] = (bf16)src[(k0 + 1) * 128 + col];
        v[2] = (bf16)src[(k0 + 2) * 128 + col];
        v[3] = (bf16)src[(k0 + 3) * 128 + col];
        *reinterpret_cast<bf16x4*>(reinterpret_cast<char*>(img) + swz_off(col, k0 * 2)) = v;
    }
}

// ---------------- CSR build ----------------

__global__ void k_hist(const int* __restrict__ senders, const int* __restrict__ receivers,
                       int* __restrict__ deg_s, int* __restrict__ deg_r) {
    int i = blockIdx.x * 256 + threadIdx.x;
    if (i < NE) {
        atomicAdd(&deg_s[senders[i]], 1);
        atomicAdd(&deg_r[receivers[i]], 1);
    }
}

__device__ void scan_arr(const int* __restrict__ deg, int* __restrict__ rs, int* __restrict__ cur,
                         int* sW, int* sRun) {
    const int tid = threadIdx.x, lane = tid & 63, wid = tid >> 6;
    if (tid == 0) *sRun = 0;
    __syncthreads();
    for (int base = 0; base < NN; base += 1024) {
        int i = base + tid;
        int orig = (i < NN) ? deg[i] : 0;
        int v = orig;
        #pragma unroll
        for (int off = 1; off < 64; off <<= 1) {
            int u = __shfl_up(v, off, 64);
            if (lane >= off) v += u;
        }
        if (lane == 63) sW[wid] = v;
        __syncthreads();
        if (wid == 0 && lane < 16) {
            int u = sW[lane];
            #pragma unroll
            for (int off = 1; off < 16; off <<= 1) {
                int t = __shfl_up(u, off, 16);
                if (lane >= off) u += t;
            }
            sW[lane] = u;
        }
        __syncthreads();
        int waveoff = (wid == 0) ? 0 : sW[wid - 1];
        int incl = v + waveoff + *sRun;
        if (i < NN) {
            rs[i + 1] = incl;
            cur[i] = incl - orig;
        }
        __syncthreads();
        if (tid == 1023) *sRun = incl;
        __syncthreads();
    }
    if (tid == 0) rs[0] = 0;
}

__global__ void k_scan(const int* __restrict__ deg_s, int* __restrict__ rs_s,
                       int* __restrict__ cur_s, const int* __restrict__ deg_r,
                       int* __restrict__ rs_r, int* __restrict__ cur_r) {
    __shared__ int sW[16];
    __shared__ int sRun;
    scan_arr(deg_s, rs_s, cur_s, sW, &sRun);
    __syncthreads();
    scan_arr(deg_r, rs_r, cur_r, sW, &sRun);
}

__global__ void k_scatter_s(const int* __restrict__ senders, const int* __restrict__ receivers,
                            int* __restrict__ cur_s, int* __restrict__ perm,
                            int* __restrict__ snd_s, int* __restrict__ rcv_s) {
    int i = blockIdx.x * 256 + threadIdx.x;
    if (i < NE) {
        int s = senders[i];
        int p = atomicAdd(&cur_s[s], 1);
        perm[p] = i;
        snd_s[p] = s;
        rcv_s[p] = receivers[i];
    }
}

__global__ void k_scatter_r(const int* __restrict__ rcv_s, int* __restrict__ cur_r,
                            int* __restrict__ csr_r) {
    int j = blockIdx.x * 256 + threadIdx.x;
    if (j < NE) {
        int r = rcv_s[j];
        int p = atomicAdd(&cur_r[r], 1);
        csr_r[p] = j;
    }
}

// ---------------- embed ----------------

__global__ void k_embed_nodes(const float* __restrict__ nodes, const float* __restrict__ W,
                              const float* __restrict__ b, float* __restrict__ n_out) {
    __shared__ float sW[64 * 128];
    __shared__ float sB[128];
    const int tid = threadIdx.x;
    for (int i = tid; i < 64 * 128; i += 256) sW[i] = W[i];
    if (tid < 128) sB[tid] = b[tid];
    __syncthreads();
    const int col = tid & 127;
    const int rh = tid >> 7;
    const int rowbase = blockIdx.x * 64;
    for (int i = 0; i < 32; ++i) {
        int row = rowbase + i * 2 + rh;
        if (row < NN) {
            const f32x4* x4 = reinterpret_cast<const f32x4*>(nodes + (size_t)row * 64);
            float a = sB[col];
            #pragma unroll
            for (int k4 = 0; k4 < 16; ++k4) {
                f32x4 xv = x4[k4];
                a += xv[0] * sW[(k4 * 4 + 0) * 128 + col];
                a += xv[1] * sW[(k4 * 4 + 1) * 128 + col];
                a += xv[2] * sW[(k4 * 4 + 2) * 128 + col];
                a += xv[3] * sW[(k4 * 4 + 3) * 128 + col];
            }
            n_out[(size_t)row * 128 + col] = a;
        }
    }
}

// Embeds edges[perm[j]] -> e[j] (bf16), applying the sender-sort permutation.
__global__ void k_embed_edges(const float* __restrict__ edges, const int* __restrict__ perm,
                              const float* __restrict__ W, const float* __restrict__ b,
                              bf16* __restrict__ e_out) {
    __shared__ float sW[16 * 128];
    __shared__ float sB[128];
    const int tid = threadIdx.x;
    for (int i = tid; i < 16 * 128; i += 256) sW[i] = W[i];
    if (tid < 128) sB[tid] = b[tid];
    __syncthreads();
    const int col = tid & 127;
    const int rh = tid >> 7;
    const int rowbase = blockIdx.x * 128;
    for (int i = 0; i < 64; ++i) {
        int row = rowbase + i * 2 + rh;
        int src = perm[row];
        const float* x = edges + (size_t)src * 16;
        float a = sB[col];
        #pragma unroll
        for (int k = 0; k < 16; ++k) a += x[k] * sW[k * 128 + col];
        e_out[(size_t)row * 128 + col] = (bf16)a;
    }
}

__global__ void k_init_glob(const float* __restrict__ globals_, const float* __restrict__ embW,
                            const float* __restrict__ embB, float* __restrict__ g,
                            const float* __restrict__ eW0g, const float* __restrict__ eb0,
                            const float* __restrict__ nW0g, const float* __restrict__ nb0,
                            float* __restrict__ gvec_e, float* __restrict__ gvec_n,
                            float* __restrict__ eagg, float* __restrict__ nagg) {
    __shared__ float sG[128];
    const int tid = threadIdx.x;  // 128 threads
    float a = embB[tid];
    #pragma unroll
    for (int k = 0; k < 8; ++k) a += globals_[k] * embW[k * 128 + tid];
    g[tid] = a;
    sG[tid] = a;
    eagg[tid] = 0.f;
    nagg[tid] = 0.f;
    __syncthreads();
    float ae = eb0[tid], an = nb0[tid];
    for (int k = 0; k < 128; ++k) {
        float gv = sG[k];
        ae += gv * eW0g[k * 128 + tid];
        an += gv * nW0g[k * 128 + tid];
    }
    gvec_e[tid] = ae;
    gvec_n[tid] = an;
}

// ---------------- per-step kernels ----------------

// Step-0 proj only: nsW = (bf16)(n @ W0b),  nrW = (bf16)(n @ W0c)
__global__ __launch_bounds__(256, 2) void k_proj(const float* __restrict__ n_in,
                                                 bf16* __restrict__ nsW, bf16* __restrict__ nrW,
                                                 const bf16* __restrict__ imgA,
                                                 const bf16* __restrict__ imgB) {
    __shared__ __align__(16) char smem[81920];
    bf16* sWa = (bf16*)smem;
    bf16* sWb = (bf16*)(smem + 32768);
    bf16* sX = (bf16*)(smem + 65536);
    const int tid = threadIdx.x;
    const int lane = tid & 63;
    const int w = tid >> 6;
    const int rowbase = blockIdx.x * 64;
    const bool wvalid = (rowbase + w * 16) < NN;

    stage_img(imgA, sWa, tid);
    stage_img(imgB, sWb, tid);
    if (wvalid) stage_rows16(n_in + (size_t)(rowbase + w * 16) * 128, sX, w * 16, lane);
    __syncthreads();
    if (!wvalid) return;

    const int arow = w * 16 + (lane & 15);
    const int kq = (lane >> 4) * 16;
    f32x4 acc[8], acc2[8];
    #pragma unroll
    for (int t = 0; t < 8; ++t) { acc[t] = f4zero(); acc2[t] = f4zero(); }
    mfma_16x128(sX, sWa, arow, kq, acc);
    mfma_16x128(sX, sWb, arow, kq, acc2);

    acc_to_lds_bf16(sX, acc, w, lane);
    lds_rows_to_global_bf16(sX, nsW + (size_t)(rowbase + w * 16) * 128, w, lane);
    acc_to_lds_bf16(sX, acc2, w, lane);
    lds_rows_to_global_bf16(sX, nrW + (size_t)(rowbase + w * 16) * 128, w, lane);
}

// Edge update: e_new = relu(relu(e@W0a + nsW[snd] + nrW[rcv] + gvec)@W1 + b1);
// e = LN(e_new + e_old). Row-space fixup/epilogue with vector gathers; no scatter atomics.
__global__ __launch_bounds__(256, 2) void k_edge(
    bf16* e_rw, bf16* __restrict__ e_new_out, const bf16* __restrict__ nsW,
    const bf16* __restrict__ nrW, float* __restrict__ edge_agg,
    const int* __restrict__ snd_s, const int* __restrict__ rcv_s,
    const bf16* __restrict__ imgW0, const bf16* __restrict__ imgW1,
    const float* __restrict__ gvec, const float* __restrict__ b1,
    const float* __restrict__ lnS, const float* __restrict__ lnO) {
    __shared__ __align__(16) char smem[81920];
    bf16* sW0 = (bf16*)smem;
    bf16* sW1 = (bf16*)(smem + 32768);
    bf16* sX = (bf16*)(smem + 65536);
    float* sEagg = (float*)(smem + 65536);  // alias; used after final barrier

    const int tid = threadIdx.x;
    const int lane = tid & 63;
    const int w = tid >> 6;  // 0..3
    const int rowbase = blockIdx.x * 64;
    const int arow = w * 16 + (lane & 15);
    const int kq = (lane >> 4) * 16;
    const int c0 = lane & 15;
    const int qrt = lane >> 4;
    const int c8 = c0 * 8;

    stage_img(imgW0, sW0, tid);
    stage_img(imgW1, sW1, tid);

    // per-lane row indices (row rl = i*4 + qrt within the wave's 16 rows)
    int snd_i[4], rcv_i[4];
    #pragma unroll
    for (int i = 0; i < 4; ++i) {
        int gr = rowbase + w * 16 + i * 4 + qrt;
        snd_i[i] = snd_s[gr];
        rcv_i[i] = rcv_s[gr];
    }
    // col-slice constants
    f32x4 gvA = *reinterpret_cast<const f32x4*>(gvec + c8);
    f32x4 gvB = *reinterpret_cast<const f32x4*>(gvec + c8 + 4);
    f32x4 lsA = *reinterpret_cast<const f32x4*>(lnS + c8);
    f32x4 lsB = *reinterpret_cast<const f32x4*>(lnS + c8 + 4);
    f32x4 loA = *reinterpret_cast<const f32x4*>(lnO + c8);
    f32x4 loB = *reinterpret_cast<const f32x4*>(lnO + c8 + 4);
    float bb[8];
    #pragma unroll
    for (int t = 0; t < 8; ++t) bb[t] = b1[t * 16 + c0];

    // stage e rows, keep e_old slices in regs
    bf16x8 eold8[4];
    {
        const bf16* src0 = e_rw + (size_t)(rowbase + w * 16) * 128;
        #pragma unroll
        for (int i = 0; i < 4; ++i) {
            int sub = i * 4 + qrt;
            eold8[i] = *reinterpret_cast<const bf16x8*>(src0 + (size_t)sub * 128 + c8);
            *reinterpret_cast<bf16x8*>(reinterpret_cast<char*>(sX) + swz_off(w * 16 + sub, c8 * 2)) =
                eold8[i];
        }
    }
    __syncthreads();

    // layer 0
    f32x4 acc[8];
    #pragma unroll
    for (int t = 0; t < 8; ++t) acc[t] = f4zero();
    mfma_16x128(sX, sW0, arow, kq, acc);

    // fragment -> LDS transpose (bias is folded into gvec)
    #pragma unroll
    for (int r = 0; r < 4; ++r) {
        int rl = w * 16 + (lane >> 4) * 4 + r;
        #pragma unroll
        for (int t = 0; t < 8; ++t)
            *reinterpret_cast<bf16*>(reinterpret_cast<char*>(sX) + swz_off(rl, (t * 16 + c0) * 2)) =
                (bf16)acc[t][r];
    }
    // row-space fixup: h = relu(a + nsW[snd] + nrW[rcv] + gvec)
    #pragma unroll
    for (int i = 0; i < 4; ++i) {
        int rl = w * 16 + i * 4 + qrt;
        bf16x8 a8 = *reinterpret_cast<const bf16x8*>(
            reinterpret_cast<const char*>(sX) + swz_off(rl, c8 * 2));
        bf16x8 ns8 = *reinterpret_cast<const bf16x8*>(nsW + (size_t)snd_i[i] * 128 + c8);
        bf16x8 nr8 = *reinterpret_cast<const bf16x8*>(nrW + (size_t)rcv_i[i] * 128 + c8);
        bf16x8 h8;
        #pragma unroll
        for (int j = 0; j < 8; ++j) {
            float gvj = (j < 4) ? gvA[j] : gvB[j - 4];
            float v = (float)a8[j] + (float)ns8[j] + (float)nr8[j] + gvj;
            h8[j] = (bf16)fmaxf(v, 0.f);
        }
        *reinterpret_cast<bf16x8*>(reinterpret_cast<char*>(sX) + swz_off(rl, c8 * 2)) = h8;
    }

    // layer 1
    f32x4 acc2[8];
    #pragma unroll
    for (int t = 0; t < 8; ++t) acc2[t] = f4zero();
    mfma_16x128(sX, sW1, arow, kq, acc2);

    // fragment -> LDS transpose with +b1, relu  (this IS e_new in bf16)
    #pragma unroll
    for (int r = 0; r < 4; ++r) {
        int rl = w * 16 + (lane >> 4) * 4 + r;
        #pragma unroll
        for (int t = 0; t < 8; ++t)
            *reinterpret_cast<bf16*>(reinterpret_cast<char*>(sX) + swz_off(rl, (t * 16 + c0) * 2)) =
                (bf16)fmaxf(acc2[t][r] + bb[t], 0.f);
    }

    // row-space epilogue: e_new store, colsum, residual + LN, e store
    float cs[8];
    #pragma unroll
    for (int j = 0; j < 8; ++j) cs[j] = 0.f;
    bf16* enew0 = e_new_out + (size_t)(rowbase + w * 16) * 128;
    bf16* e0 = e_rw + (size_t)(rowbase + w * 16) * 128;
    #pragma unroll
    for (int i = 0; i < 4; ++i) {
        int sub = i * 4 + qrt;
        bf16x8 en8 = *reinterpret_cast<const bf16x8*>(
            reinterpret_cast<const char*>(sX) + swz_off(w * 16 + sub, c8 * 2));
        *reinterpret_cast<bf16x8*>(enew0 + (size_t)sub * 128 + c8) = en8;
        float rv[8], s1 = 0.f, s2 = 0.f;
        #pragma unroll
        for (int j = 0; j < 8; ++j) {
            float en = (float)en8[j];
            cs[j] += en;
            float v = en + (float)eold8[i][j];
            rv[j] = v;
            s1 += v;
            s2 += v * v;
        }
        #pragma unroll
        for (int off = 1; off < 16; off <<= 1) {
            s1 += __shfl_xor(s1, off, 16);
            s2 += __shfl_xor(s2, off, 16);
        }
        float mean = s1 * (1.f / 128.f);
        float rstd = rsqrtf(s2 * (1.f / 128.f) - mean * mean + LN_EPS);
        bf16x8 o8;
        #pragma unroll
        for (int j = 0; j < 8; ++j) {
            float ls = (j < 4) ? lsA[j] : lsB[j - 4];
            float lo = (j < 4) ? loA[j] : loB[j - 4];
            o8[j] = (bf16)((rv[j] - mean) * rstd * ls + lo);
        }
        *reinterpret_cast<bf16x8*>(e0 + (size_t)sub * 128 + c8) = o8;
    }

    // block edge_agg reduction
    #pragma unroll
    for (int j = 0; j < 8; ++j) {
        cs[j] += __shfl_xor(cs[j], 16, 64);
        cs[j] += __shfl_xor(cs[j], 32, 64);
    }
    __syncthreads();
    if (qrt == 0) {
        float* dst = sEagg + w * 128 + c8;
        #pragma unroll
        for (int j = 0; j < 8; ++j) dst[j] = cs[j];
    }
    __syncthreads();
    if (tid < 128) {
        float v = sEagg[tid] + sEagg[128 + tid] + sEagg[256 + tid] + sEagg[384 + tid];
        atomicAdd(&edge_agg[tid], v);
    }
}

// Two-sided aggregation: sent (contiguous segments) + recv (CSR gather), bf16 out, 16B/lane.
__global__ __launch_bounds__(256) void k_agg(const bf16* __restrict__ e_new,
                                             const int* __restrict__ rs_s,
                                             const int* __restrict__ rs_r,
                                             const int* __restrict__ csr_r,
                                             bf16* __restrict__ sent, bf16* __restrict__ recv) {
    const int lane = threadIdx.x & 63;
    const int w = threadIdx.x >> 6;
    const int node = blockIdx.x * 4 + w;
    if (node >= NN) return;
    const int qrt = lane >> 4;
    const int c8 = (lane & 15) * 8;
    float a[8];
    #pragma unroll
    for (int j = 0; j < 8; ++j) a[j] = 0.f;
    const int b0 = rs_s[node], b1 = rs_s[node + 1];
    for (int jj = b0 + qrt; jj < b1; jj += 4) {
        bf16x8 v = *reinterpret_cast<const bf16x8*>(e_new + (size_t)jj * 128 + c8);
        #pragma unroll
        for (int j = 0; j < 8; ++j) a[j] += (float)v[j];
    }
    #pragma unroll
    for (int j = 0; j < 8; ++j) {
        a[j] += __shfl_xor(a[j], 16, 64);
        a[j] += __shfl_xor(a[j], 32, 64);
    }
    if (qrt == 0) {
        bf16x8 o;
        #pragma unroll
        for (int j = 0; j < 8; ++j) o[j] = (bf16)a[j];
        *reinterpret_cast<bf16x8*>(sent + (size_t)node * 128 + c8) = o;
    }
    #pragma unroll
    for (int j = 0; j < 8; ++j) a[j] = 0.f;
    const int c1 = rs_r[node], c2 = rs_r[node + 1];
    for (int pp = c1 + qrt; pp < c2; pp += 4) {
        int jj = csr_r[pp];
        bf16x8 v = *reinterpret_cast<const bf16x8*>(e_new + (size_t)jj * 128 + c8);
        #pragma unroll
        for (int j = 0; j < 8; ++j) a[j] += (float)v[j];
    }
    #pragma unroll
    for (int j = 0; j < 8; ++j) {
        a[j] += __shfl_xor(a[j], 16, 64);
        a[j] += __shfl_xor(a[j], 32, 64);
    }
    if (qrt == 0) {
        bf16x8 o;
        #pragma unroll
        for (int j = 0; j < 8; ++j) o[j] = (bf16)a[j];
        *reinterpret_cast<bf16x8*>(recv + (size_t)node * 128 + c8) = o;
    }
}

// Node update: n = LN(relu(relu(n@A + sa@B + ra@C + gvec)@W1 + b1) + n).
// Optionally fuses next step's projections nsW/nrW from the LN'd n held in LDS.
__global__ __launch_bounds__(256, 2) void k_node(
    float* n_rw, const bf16* __restrict__ sent_agg, const bf16* __restrict__ recv_agg,
    float* __restrict__ node_agg, const bf16* __restrict__ imgW0, const bf16* __restrict__ imgW1,
    const float* __restrict__ gvec, const float* __restrict__ b1,
    const float* __restrict__ lnS, const float* __restrict__ lnO,
    const bf16* __restrict__ imgPs, const bf16* __restrict__ imgPr,
    bf16* __restrict__ nsW, bf16* __restrict__ nrW, int do_proj) {
    __shared__ __align__(16) char smem[81920];
    bf16* sW0 = (bf16*)smem;
    bf16* sW1 = (bf16*)(smem + 32768);
    bf16* sX = (bf16*)(smem + 65536);
    float* sNagg = (float*)(smem + 65536);  // alias; used after final barrier

    const int tid = threadIdx.x;
    const int lane = tid & 63;
    const int w = tid >> 6;
    const int rowbase = blockIdx.x * 64;
    const bool wvalid = (rowbase + w * 16) < NN;
    const int arow = w * 16 + (lane & 15);
    const int kq = (lane >> 4) * 16;
    const int c0 = lane & 15;
    const int qrt = lane >> 4;
    const int c8 = c0 * 8;

    stage_img(imgW1, sW1, tid);

    f32x4 acc[8];
    #pragma unroll
    for (int t = 0; t < 8; ++t) acc[t] = f4zero();

    #pragma unroll
    for (int c = 0; c < 3; ++c) {
        __syncthreads();
        stage_img(imgW0 + (size_t)c * 16384, sW0, tid);
        if (wvalid) {
            if (c == 0)
                stage_rows16(n_rw + (size_t)(rowbase + w * 16) * 128, sX, w * 16, lane);
            else
                stage_rows16_bf16(((c == 1) ? sent_agg : recv_agg) +
                                      (size_t)(rowbase + w * 16) * 128,
                                  sX, w * 16, lane);
        }
        __syncthreads();
        if (wvalid) mfma_16x128(sX, sW0, arow, kq, acc);
    }

    float gvf[8], bbf[8];
    #pragma unroll
    for (int t = 0; t < 8; ++t) {
        gvf[t] = gvec[t * 16 + c0];
        bbf[t] = b1[t * 16 + c0];
    }
    f32x4 lsA = *reinterpret_cast<const f32x4*>(lnS + c8);
    f32x4 lsB = *reinterpret_cast<const f32x4*>(lnS + c8 + 4);
    f32x4 loA = *reinterpret_cast<const f32x4*>(lnO + c8);
    f32x4 loB = *reinterpret_cast<const f32x4*>(lnO + c8 + 4);

    // fixup (gvec is per-col; fragment space, no transpose needed)
    if (wvalid) {
        #pragma unroll
        for (int r = 0; r < 4; ++r) {
            int rl = w * 16 + (lane >> 4) * 4 + r;
            #pragma unroll
            for (int t = 0; t < 8; ++t)
                *reinterpret_cast<bf16*>(reinterpret_cast<char*>(sX) +
                                         swz_off(rl, (t * 16 + c0) * 2)) =
                    (bf16)fmaxf(acc[t][r] + gvf[t], 0.f);
        }
    }

    // layer 1
    f32x4 acc2[8];
    #pragma unroll
    for (int t = 0; t < 8; ++t) acc2[t] = f4zero();
    float cs[8];
    #pragma unroll
    for (int j = 0; j < 8; ++j) cs[j] = 0.f;
    if (wvalid) {
        mfma_16x128(sX, sW1, arow, kq, acc2);
        // fragment -> LDS transpose with +b1, relu  (n_new bf16)
        #pragma unroll
        for (int r = 0; r < 4; ++r) {
            int rl = w * 16 + (lane >> 4) * 4 + r;
            #pragma unroll
            for (int t = 0; t < 8; ++t)
                *reinterpret_cast<bf16*>(reinterpret_cast<char*>(sX) +
                                         swz_off(rl, (t * 16 + c0) * 2)) =
                    (bf16)fmaxf(acc2[t][r] + bbf[t], 0.f);
        }
        // row-space epilogue: colsum, residual + LN; n (f32) store; LN bf16 back to sX for proj
        const float* nbase = n_rw + (size_t)(rowbase + w * 16) * 128;
        #pragma unroll
        for (int i = 0; i < 4; ++i) {
            int sub = i * 4 + qrt;
            bf16x8 en8 = *reinterpret_cast<const bf16x8*>(
                reinterpret_cast<const char*>(sX) + swz_off(w * 16 + sub, c8 * 2));
            f32x4 noA = *reinterpret_cast<const f32x4*>(nbase + (size_t)sub * 128 + c8);
            f32x4 noB = *reinterpret_cast<const f32x4*>(nbase + (size_t)sub * 128 + c8 + 4);
            float rv[8], s1 = 0.f, s2 = 0.f;
            #pragma unroll
            for (int j = 0; j < 8; ++j) {
                float en = (float)en8[j];
                cs[j] += en;
                float v = en + ((j < 4) ? noA[j] : noB[j - 4]);
                rv[j] = v;
                s1 += v;
                s2 += v * v;
            }
            #pragma unroll
            for (int off = 1; off < 16; off <<= 1) {
                s1 += __shfl_xor(s1, off, 16);
                s2 += __shfl_xor(s2, off, 16);
            }
            float mean = s1 * (1.f / 128.f);
            float rstd = rsqrtf(s2 * (1.f / 128.f) - mean * mean + LN_EPS);
            f32x4 oA, oB;
            bf16x8 l8;
            #pragma unroll
            for (int j = 0; j < 8; ++j) {
                float ls = (j < 4) ? lsA[j] : lsB[j - 4];
                float lo = (j < 4) ? loA[j] : loB[j - 4];
                float o = (rv[j] - mean) * rstd * ls + lo;
                if (j < 4) oA[j] = o; else oB[j - 4] = o;
                l8[j] = (bf16)o;
            }
            float* orow = n_rw + (size_t)(rowbase + w * 16 + sub) * 128 + c8;
            *reinterpret_cast<f32x4*>(orow) = oA;
            *reinterpret_cast<f32x4*>(orow + 4) = oB;
            *reinterpret_cast<bf16x8*>(reinterpret_cast<char*>(sX) +
                                       swz_off(w * 16 + sub, c8 * 2)) = l8;
        }
    }

    // fused next-step projections from LN'd n in sX
    if (do_proj) {
        __syncthreads();
        stage_img(imgPs, sW0, tid);
        stage_img(imgPr, sW1, tid);
        __syncthreads();
        if (wvalid) {
            f32x4 pa[8], pb[8];
            #pragma unroll
            for (int t = 0; t < 8; ++t) { pa[t] = f4zero(); pb[t] = f4zero(); }
            mfma_16x128(sX, sW0, arow, kq, pa);
            mfma_16x128(sX, sW1, arow, kq, pb);
            acc_to_lds_bf16(sX, pa, w, lane);
            lds_rows_to_global_bf16(sX, nsW + (size_t)(rowbase + w * 16) * 128, w, lane);
            acc_to_lds_bf16(sX, pb, w, lane);
            lds_rows_to_global_bf16(sX, nrW + (size_t)(rowbase + w * 16) * 128, w, lane);
        }
    }

    // node_agg reduction
    #pragma unroll
    for (int j = 0; j < 8; ++j) {
        cs[j] += __shfl_xor(cs[j], 16, 64);
        cs[j] += __shfl_xor(cs[j], 32, 64);
    }
    __syncthreads();
    if (qrt == 0) {
        float* dst = sNagg + w * 128 + c8;
        #pragma unroll
        for (int j = 0; j < 8; ++j) dst[j] = cs[j];
    }
    __syncthreads();
    if (tid < 128) {
        float v = sNagg[tid] + sNagg[128 + tid] + sNagg[256 + tid] + sNagg[384 + tid];
        atomicAdd(&node_agg[tid], v);
    }
}

// Global update (1 block, 256 threads) + next-step gvec + agg re-zero + optional decode.
__global__ void k_glob(float* __restrict__ g, float* __restrict__ node_agg,
                       float* __restrict__ edge_agg, const float* __restrict__ W0,
                       const float* __restrict__ b0, const float* __restrict__ W1,
                       const float* __restrict__ b1, const float* __restrict__ lnS,
                       const float* __restrict__ lnO, const float* __restrict__ eW0g,
                       const float* __restrict__ eb0, const float* __restrict__ nW0g,
                       const float* __restrict__ nb0, float* __restrict__ gvec_e,
                       float* __restrict__ gvec_n, const float* __restrict__ decW,
                       const float* __restrict__ decb, float* __restrict__ out, int do_next,
                       int do_dec) {
    __shared__ float sP[2][128];
    __shared__ float sH[128];
    __shared__ float sG[128];
    __shared__ float sMR[2];
    const int tid = threadIdx.x;
    const int j = tid & 127;
    const int half = tid >> 7;

    float p = 0.f;
    for (int k = 0; k < 64; ++k) {
        int kk = half * 64 + k;
        p += node_agg[kk] * W0[kk * 128 + j];
        p += edge_agg[kk] * W0[(128 + kk) * 128 + j];
        p += g[kk] * W0[(256 + kk) * 128 + j];
    }
    sP[half][j] = p;
    __syncthreads();
    if (tid < 128) {  // re-zero aggregates for the next step
        node_agg[tid] = 0.f;
        edge_agg[tid] = 0.f;
    }
    if (half == 0) sH[j] = fmaxf(b0[j] + sP[0][j] + sP[1][j], 0.f);
    __syncthreads();
    p = 0.f;
    for (int k = 0; k < 64; ++k) {
        int kk = half * 64 + k;
        p += sH[kk] * W1[kk * 128 + j];
    }
    sP[half][j] = p;
    __syncthreads();
    float res = 0.f;
    if (half == 0) {
        float gn = fmaxf(b1[j] + sP[0][j] + sP[1][j], 0.f);
        res = gn + g[j];
    }
    __syncthreads();
    if (half == 0) {
        sP[0][j] = res;
        sP[1][j] = res * res;
    }
    __syncthreads();
    if (tid < 64) {
        float a = sP[0][tid] + sP[0][tid + 64];
        float q = sP[1][tid] + sP[1][tid + 64];
        #pragma unroll
        for (int off = 1; off < 64; off <<= 1) {
            a += __shfl_xor(a, off, 64);
            q += __shfl_xor(q, off, 64);
        }
        if (tid == 0) {
            float m = a * (1.f / 128.f);
            float v = q * (1.f / 128.f) - m * m;
            sMR[0] = m;
            sMR[1] = rsqrtf(v + LN_EPS);
        }
    }
    __syncthreads();
    if (half == 0) {
        float go = (res - sMR[0]) * sMR[1] * lnS[j] + lnO[j];
        g[j] = go;
        sG[j] = go;
    }
    __syncthreads();
    if (do_next && half == 0) {
        float ae = eb0[j], an = nb0[j];
        for (int k = 0; k < 128; ++k) {
            float gv = sG[k];
            ae += gv * eW0g[k * 128 + j];
            an += gv * nW0g[k * 128 + j];
        }
        gvec_e[j] = ae;
        gvec_n[j] = an;
    }
    if (do_dec && tid < 8) {
        float a = decb[tid];
        for (int k = 0; k < 128; ++k) a += sG[k] * decW[k * 8 + tid];
        out[tid] = a;
    }
}

extern "C" void kernel_launch(void* const* d_in, const int* in_sizes, int n_in, void* d_out,
                              int out_size, void* d_ws, size_t ws_size, hipStream_t stream) {
    (void)in_sizes; (void)n_in; (void)out_size; (void)ws_size;
    const float* nodes = (const float*)d_in[0];
    const float* edges = (const float*)d_in[1];
    const float* globals_ = (const float*)d_in[2];
    const int* senders = (const int*)d_in[3];
    const int* receivers = (const int*)d_in[4];
    const float* emb_node_W = (const float*)d_in[5];
    const float* emb_node_b = (const float*)d_in[6];
    const float* emb_edge_W = (const float*)d_in[7];
    const float* emb_edge_b = (const float*)d_in[8];
    const float* emb_glob_W = (const float*)d_in[9];
    const float* emb_glob_b = (const float*)d_in[10];
    const float* edge_W0 = (const float*)d_in[11];
    const float* edge_b0 = (const float*)d_in[12];
    const float* edge_W1 = (const float*)d_in[13];
    const float* edge_b1 = (const float*)d_in[14];
    const float* node_W0 = (const float*)d_in[15];
    const float* node_b0 = (const float*)d_in[16];
    const float* node_W1 = (const float*)d_in[17];
    const float* node_b1 = (const float*)d_in[18];
    const float* glob_W0 = (const float*)d_in[19];
    const float* glob_b0 = (const float*)d_in[20];
    const float* glob_W1 = (const float*)d_in[21];
    const float* glob_b1 = (const float*)d_in[22];
    const float* ln_scale = (const float*)d_in[23];
    const float* ln_offset = (const float*)d_in[24];
    const float* dec_W = (const float*)d_in[25];
    const float* dec_b = (const float*)d_in[26];

    char* ws = (char*)d_ws;
    size_t off = 0;
    auto alloc = [&](size_t bytes) -> char* {
        char* p = ws + off;
        off += (bytes + 255) & ~(size_t)255;
        return p;
    };
    bf16* e = (bf16*)alloc((size_t)NE * NL * 2);
    bf16* e_new = (bf16*)alloc((size_t)NE * NL * 2);
    float* n = (float*)alloc((size_t)NN * NL * 4);
    bf16* nsW = (bf16*)alloc((size_t)NN * NL * 2);
    bf16* nrW = (bf16*)alloc((size_t)NN * NL * 2);
    bf16* sent = (bf16*)alloc((size_t)NN * NL * 2);
    bf16* recv = (bf16*)alloc((size_t)NN * NL * 2);
    bf16* imgs = (bf16*)alloc((size_t)24 * 16384 * 2);
    float* eagg = (float*)alloc(128 * 4);
    float* nagg = (float*)alloc(128 * 4);
    float* g = (float*)alloc(128 * 4);
    float* gve = (float*)alloc(128 * 4);
    float* gvn = (float*)alloc(128 * 4);
    int* deg = (int*)alloc((size_t)2 * NN * 4);  // deg_s | deg_r contiguous
    int* deg_s = deg;
    int* deg_r = deg + NN;
    int* rs_s = (int*)alloc((size_t)(NN + 1) * 4);
    int* rs_r = (int*)alloc((size_t)(NN + 1) * 4);
    int* cur_s = (int*)alloc((size_t)NN * 4);
    int* cur_r = (int*)alloc((size_t)NN * 4);
    int* perm = (int*)alloc((size_t)NE * 4);
    int* snd_s = (int*)alloc((size_t)NE * 4);
    int* rcv_s = (int*)alloc((size_t)NE * 4);
    int* csr_r = (int*)alloc((size_t)NE * 4);

    const int NB_N = (NN + 63) / 64;     // 157
    const int NB_E = NE / 64;            // 2500
    const int NB_EMB = NE / 128;         // 1250
    const int NB_SC = (NE + 255) / 256;  // 625
    const int NB_AGG = NN / 4;           // 2500

    auto img = [&](int s, int kind) -> const bf16* {
        return imgs + ((size_t)s * 8 + kind) * 16384;
    };

    k_prep<<<24, 256, 0, stream>>>(edge_W0, edge_W1, node_W0, node_W1, imgs);

    // CSR build (per call; atomic within-segment order only perturbs fp rounding)
    hipMemsetAsync(deg, 0, (size_t)2 * NN * 4, stream);
    k_hist<<<NB_SC, 256, 0, stream>>>(senders, receivers, deg_s, deg_r);
    k_scan<<<1, 1024, 0, stream>>>(deg_s, rs_s, cur_s, deg_r, rs_r, cur_r);
    k_scatter_s<<<NB_SC, 256, 0, stream>>>(senders, receivers, cur_s, perm, snd_s, rcv_s);
    k_scatter_r<<<NB_SC, 256, 0, stream>>>(rcv_s, cur_r, csr_r);

    k_embed_nodes<<<NB_N, 256, 0, stream>>>(nodes, emb_node_W, emb_node_b, n);
    k_embed_edges<<<NB_EMB, 256, 0, stream>>>(edges, perm, emb_edge_W, emb_edge_b, e);
    k_init_glob<<<1, 128, 0, stream>>>(globals_, emb_glob_W, emb_glob_b, g,
                                       edge_W0 + 384 * 128, edge_b0, node_W0 + 384 * 128,
                                       node_b0, gve, gvn, eagg, nagg);
    k_proj<<<NB_N, 256, 0, stream>>>(n, nsW, nrW, img(0, 1), img(0, 2));

    for (int s = 0; s < 3; ++s) {
        const int last = (s == 2);
        k_edge<<<NB_E, 256, 0, stream>>>(e, e_new, nsW, nrW, eagg, snd_s, rcv_s, img(s, 0),
                                         img(s, 3), gve, edge_b1 + s * 128,
                                         ln_scale + (s * 3 + 1) * 128,
                                         ln_offset + (s * 3 + 1) * 128);
        k_agg<<<NB_AGG, 256, 0, stream>>>(e_new, rs_s, rs_r, csr_r, sent, recv);
        k_node<<<NB_N, 256, 0, stream>>>(n, sent, recv, nagg, img(s, 4), img(s, 7), gvn,
                                         node_b1 + s * 128, ln_scale + (s * 3 + 0) * 128,
                                         ln_offset + (s * 3 + 0) * 128,
                                         img(last ? 0 : s + 1, 1), img(last ? 0 : s + 1, 2),
                                         nsW, nrW, !last);
        const float* eW0g = last ? edge_W0 : edge_W0 + (size_t)(s + 1) * 512 * 128 + 384 * 128;
        const float* eb0n = last ? edge_b0 : edge_b0 + (s + 1) * 128;
        const float* nW0g = last ? node_W0 : node_W0 + (size_t)(s + 1) * 512 * 128 + 384 * 128;
        const float* nb0n = last ? node_b0 : node_b0 + (s + 1) * 128;
        k_glob<<<1, 256, 0, stream>>>(g, nagg, eagg, glob_W0 + (size_t)s * 384 * 128,
                                      glob_b0 + s * 128, glob_W1 + (size_t)s * 128 * 128,
                                      glob_b1 + s * 128, ln_scale + (s * 3 + 2) * 128,
                                      ln_offset + (s * 3 + 2) * 128, eW0g, eb0n, nW0g, nb0n,
                                      gve, gvn, dec_W, dec_b, (float*)d_out, !last, last);
    }
}